// Round 2
// baseline (311.116 us; speedup 1.0000x reference)
//
#include <hip/hip_runtime.h>

// ---------------------------------------------------------------------------
// HTGT layer: sort-by-type + bf16 MFMA pipeline
// dims (fixed by problem): N=50000 M=10000 E=100000, in=128 e=32 out=128 td=32
// R=8 etypes, T=4 ntypes, H=8 heads, hs=16
// R2: k_hist/k_scatter hot-counter atomics hierarchized
// R3: register-resident-B GEMMs (fragment-major weights, no Bt LDS staging)
// R4: k_prep fused into k_qkv. LN results are computed straight into the LDS
//     A-tiles (no dia_s/dia_d HBM round trip: -115MB traffic, -1 launch).
//     LN uses single-pass sum/sumsq (var = E[x^2]-mu^2) so the 4 wave
//     butterflies (s1,s2,t1,t2) are independent and interleave; pair-per-lane
//     float2 loads + packed ushort2 LDS stores.
// ---------------------------------------------------------------------------

typedef __attribute__((ext_vector_type(8))) short short8;
typedef __attribute__((ext_vector_type(4))) float f32x4;

__device__ __forceinline__ unsigned short f2bf(float f){
  union { float f; unsigned u; } x; x.f = f;
  unsigned r = x.u + 0x7FFFu + ((x.u >> 16) & 1u);
  return (unsigned short)(r >> 16);
}
__device__ __forceinline__ float bf2f(unsigned short b){
  union { unsigned u; float f; } x; x.u = ((unsigned)b) << 16;
  return x.f;
}

// ---------------- setup kernels ----------------

__global__ void k_zero(int* __restrict__ p, int n){
  int i = blockIdx.x*256 + threadIdx.x;
  if(i < n) p[i] = 0;
}

__global__ __launch_bounds__(256) void k_hist(
    const int* __restrict__ etype, const int* __restrict__ dst_idx,
    const int* __restrict__ ntype,
    int* cnt_e, int* cnt_d, int* cnt_n, int E, int M){
  __shared__ int le[8], ln[4];
  int tid = threadIdx.x;
  if(tid < 8) le[tid] = 0;
  if(tid < 4) ln[tid] = 0;
  __syncthreads();
  int g = blockIdx.x*256 + tid;
  if(g < E){ atomicAdd(&le[etype[g]], 1); atomicAdd(&cnt_d[dst_idx[g]], 1); }
  if(g < M){ atomicAdd(&ln[ntype[g]], 1); }
  __syncthreads();
  if(tid < 8 && le[tid]) atomicAdd(&cnt_e[tid], le[tid]);
  if(tid < 4 && ln[tid]) atomicAdd(&cnt_n[tid], ln[tid]);
}

__global__ __launch_bounds__(1024) void k_scan(const int* __restrict__ cnt_e, int* off_e,
                                               const int* __restrict__ cnt_n, int* off_n,
                                               const int* __restrict__ cnt_d, int* off_d, int M){
  __shared__ int part[1024];
  int tid = threadIdx.x;
  if(tid == 0){
    int s = 0;
    for(int i=0;i<8;i++){ off_e[i]=s; s+=cnt_e[i]; } off_e[8]=s;
    s = 0;
    for(int i=0;i<4;i++){ off_n[i]=s; s+=cnt_n[i]; } off_n[4]=s;
  }
  int per = (M + 1023) >> 10;
  int s = 0;
  for(int j=0;j<per;j++){ int idx = tid*per + j; if(idx < M) s += cnt_d[idx]; }
  part[tid] = s; __syncthreads();
  for(int o=1;o<1024;o<<=1){
    int v = (tid >= o) ? part[tid-o] : 0;
    __syncthreads();
    part[tid] += v;
    __syncthreads();
  }
  int run = (tid == 0) ? 0 : part[tid-1];
  for(int j=0;j<per;j++){
    int idx = tid*per + j;
    if(idx < M){ off_d[idx] = run; run += cnt_d[idx]; }
  }
  if(tid == 1023) off_d[M] = run;
}

__global__ __launch_bounds__(256) void k_scatter(
    const int* __restrict__ etype, const int* __restrict__ dst_idx,
    const int* __restrict__ ntype,
    const int* __restrict__ off_e, int* cur_e,
    const int* __restrict__ off_d, int* cur_d,
    const int* __restrict__ off_n, int* cur_n,
    int* eperm, int* dstlist, int* nperm, int* npos, int E, int M){
  __shared__ int lcnt[8], lbase[8], lnc[4], lnb[4];
  int tid = threadIdx.x;
  if(tid < 8) lcnt[tid] = 0;
  if(tid < 4) lnc[tid] = 0;
  __syncthreads();
  int g = blockIdx.x*256 + tid;
  int r = 0, lrank = 0, t = 0, nrank = 0;
  bool inE = (g < E), inM = (g < M);
  if(inE){ r = etype[g]; lrank = atomicAdd(&lcnt[r], 1); }
  if(inM){ t = ntype[g]; nrank = atomicAdd(&lnc[t], 1); }
  __syncthreads();
  if(tid < 8 && lcnt[tid]) lbase[tid] = atomicAdd(&cur_e[tid], lcnt[tid]);
  if(tid < 4 && lnc[tid])  lnb[tid]   = atomicAdd(&cur_n[tid], lnc[tid]);
  __syncthreads();
  if(inE){
    int p = off_e[r] + lbase[r] + lrank;
    eperm[p] = g;
    int d = dst_idx[g];
    int q = off_d[d] + atomicAdd(&cur_d[d], 1);   // ~10-way contention, benign
    dstlist[q] = p;                               // etype-sorted position
  }
  if(inM){
    int np = off_n[t] + lnb[t] + nrank;
    npos[g] = np;
    nperm[np] = g;
  }
}

// convert weights to bf16 FRAGMENT-MAJOR layout:
//   [r][nb][c][quad][m][j]  (n = nb*16+m = out col, k = c*32+quad*8+j = in dim)
// so that wave w's B-fragment for chunk c is one contiguous, coalesced 1KB
// block: lane l (l = quad*16+m) reads 16B at block_base + l*16.
__global__ void k_convw(const float* __restrict__ Wq, const float* __restrict__ Wk,
                        const float* __restrict__ Wv, const float* __restrict__ Wa,
                        unsigned short* Wq_t, unsigned short* Wk_t,
                        unsigned short* Wv_t, unsigned short* Wa_t){
  int tid = blockIdx.x*256 + threadIdx.x;
  if(tid < 131072){                                  // Wq: 8 x 128(k) x 128(n)
    int r = tid >> 14, rem = tid & 16383, k = rem >> 7, n = rem & 127;
    int nb=n>>4, m=n&15, c=k>>5, quad=(k>>3)&3, j=k&7;
    Wq_t[r*16384 + ((nb*4 + c)*4 + quad)*128 + m*8 + j] = f2bf(Wq[tid]);
  } else if(tid < 294912){                           // Wk: 8 x 160(k) x 128(n)
    int u = tid - 131072;
    int r = u / 20480, rem = u - r*20480, k = rem >> 7, n = rem & 127;
    int nb=n>>4, m=n&15, c=k>>5, quad=(k>>3)&3, j=k&7;
    Wk_t[r*20480 + ((nb*5 + c)*4 + quad)*128 + m*8 + j] = f2bf(Wk[u]);
  } else if(tid < 458752){                           // Wv: 8 x 160(k) x 128(n)
    int u = tid - 294912;
    int r = u / 20480, rem = u - r*20480, k = rem >> 7, n = rem & 127;
    int nb=n>>4, m=n&15, c=k>>5, quad=(k>>3)&3, j=k&7;
    Wv_t[r*20480 + ((nb*5 + c)*4 + quad)*128 + m*8 + j] = f2bf(Wv[u]);
  } else if(tid < 524288){                           // Wa: 4 x 128(k) x 128(n)
    int u = tid - 458752;
    int r = u >> 14, rem = u & 16383, k = rem >> 7, n = rem & 127;
    int nb=n>>4, m=n&15, c=k>>5, quad=(k>>3)&3, j=k&7;
    Wa_t[r*16384 + ((nb*4 + c)*4 + quad)*128 + m*8 + j] = f2bf(Wa[u]);
  }
}

// ---------------- shared GEMM core: 64 rows x 128 cols, wave = 64 rows x 32 cols
// A in LDS [64][lda] bf16 (staged + synced by caller, read-only here);
// Wf global bf16 in fragment-major layout; B lives in registers, no barriers.
template<int NC>
__device__ __forceinline__ void gemm64r(
  const unsigned short* __restrict__ A, int lda,
  const unsigned short* __restrict__ Wf,
  f32x4* acc, int tid)
{
  int lane = tid & 63, w = tid >> 6, m = lane & 15, quad = lane >> 4;
  // per-wave B fragments: nb=2w (cols w*32..w*32+15), nb=2w+1 (cols +16..+31)
  const unsigned short* p0 = Wf + (size_t)(2*w)*NC*512 + lane*8;
  short8 b0[NC], b1[NC];
  #pragma unroll
  for(int c=0;c<NC;c++){
    b0[c] = *(const short8*)(p0 + c*512);
    b1[c] = *(const short8*)(p0 + NC*512 + c*512);
  }
  #pragma unroll
  for(int i=0;i<8;i++) acc[i] = (f32x4){0.f,0.f,0.f,0.f};
  #pragma unroll
  for(int c=0;c<NC;c++){
    #pragma unroll
    for(int rt=0; rt<4; rt++){
      short8 af = *(const short8*)(A + (rt*16 + m)*lda + c*32 + quad*8);
      acc[rt*2+0] = __builtin_amdgcn_mfma_f32_16x16x32_bf16(af, b0[c], acc[rt*2+0], 0,0,0);
      acc[rt*2+1] = __builtin_amdgcn_mfma_f32_16x16x32_bf16(af, b1[c], acc[rt*2+1], 0,0,0);
    }
  }
}

// ---------------- fused prep (gather + temporal encode + LN -> LDS)
//                  + typed q/k/v GEMM + attention scores
__global__ __launch_bounds__(256) void k_qkv(
  const float* __restrict__ src_h, const float* __restrict__ src_tw, const float* __restrict__ src_tb,
  const float* __restrict__ edge_h, const float* __restrict__ date,
  const int* __restrict__ src_idx, const int* __restrict__ dst_idx, const int* __restrict__ eperm,
  const float* __restrict__ g_s, const float* __restrict__ b_s,
  const float* __restrict__ g_d, const float* __restrict__ b_d,
  const unsigned short* __restrict__ Wq_t, const unsigned short* __restrict__ Wk_t,
  const unsigned short* __restrict__ Wv_t,
  const int* __restrict__ cnt_e, const int* __restrict__ off_e,
  float* __restrict__ abuf, unsigned short* __restrict__ vbuf)
{
  __shared__ unsigned short Ad[64*136];
  __shared__ unsigned short As[64*168];
  int bid = blockIdx.x;
  int r = -1, tl0 = 0, accT = 0;
  #pragma unroll
  for(int i=0;i<8;i++){
    int n = cnt_e[i], tt = (n + 63) >> 6;
    if(r < 0 && bid < accT + tt){ r = i; tl0 = bid - accT; }
    accT += tt;
  }
  if(r < 0) return;
  int row0 = off_e[r] + tl0*64;
  int nv = min(64, cnt_e[r] - tl0*64);
  int tid = threadIdx.x;
  int lane = tid & 63, w = tid >> 6, m = lane & 15, quad = lane >> 4;

  // ---- prep phase: wave w computes rows w, w+4, ... into Ad/As ----
  {
    // loop-invariant LN params (pair per lane)
    float2 gs01 = *(const float2*)(g_s + 2*lane);
    float2 bs01 = *(const float2*)(b_s + 2*lane);
    float2 gd01 = *(const float2*)(g_d + 2*lane);
    float2 bd01 = *(const float2*)(b_d + 2*lane);
    float gs2 = 0.f, bs2 = 0.f;
    if(lane < 32){ gs2 = g_s[128+lane]; bs2 = b_s[128+lane]; }
    for(int row = w; row < 64; row += 4){
      unsigned* as_pair = (unsigned*)(As + row*168);
      unsigned* ad_pair = (unsigned*)(Ad + row*136);
      if(row < nv){
        int e = eperm[row0 + row];
        float t = date[e];
        int s = src_idx[e], d = dst_idx[e];
        float2 hs = *(const float2*)(src_h + (size_t)s*128 + 2*lane);
        float2 hd = *(const float2*)(src_h + (size_t)d*128 + 2*lane);
        float xe = 0.f;
        if(lane < 32) xe = edge_h[(size_t)e*32 + lane];
        float sx0 = hs.x, sx1 = hs.y, dx0 = hd.x, dx1 = hd.y;
        if(lane < 16){
          float2 tws = *(const float2*)(src_tw + (size_t)s*32 + 2*lane);
          float2 tbs = *(const float2*)(src_tb + (size_t)s*32 + 2*lane);
          float2 twd = *(const float2*)(src_tw + (size_t)d*32 + 2*lane);
          float2 tbd = *(const float2*)(src_tb + (size_t)d*32 + 2*lane);
          sx0 = __sinf(tws.x*t + tbs.x) * hs.x;
          sx1 = __sinf(tws.y*t + tbs.y) * hs.y;
          dx0 = __sinf(twd.x*t + tbd.x) * hd.x;
          dx1 = __sinf(twd.y*t + tbd.y) * hd.y;
        }
        // independent sum/sumsq butterflies (var = E[x^2]-mu^2)
        float s1 = sx0 + sx1 + xe;
        float s2 = sx0*sx0 + sx1*sx1 + xe*xe;
        float t1 = dx0 + dx1;
        float t2 = dx0*dx0 + dx1*dx1;
        #pragma unroll
        for(int i=1;i<64;i<<=1){
          s1 += __shfl_xor(s1,i); s2 += __shfl_xor(s2,i);
          t1 += __shfl_xor(t1,i); t2 += __shfl_xor(t2,i);
        }
        float smu = s1*(1.f/160.f);
        float ssc = rsqrtf(s2*(1.f/160.f) - smu*smu + 1e-5f);
        float dmu = t1*(1.f/128.f);
        float dsc = rsqrtf(t2*(1.f/128.f) - dmu*dmu + 1e-5f);
        unsigned short y0 = f2bf((sx0-smu)*ssc*gs01.x + bs01.x);
        unsigned short y1 = f2bf((sx1-smu)*ssc*gs01.y + bs01.y);
        as_pair[lane] = (unsigned)y0 | ((unsigned)y1 << 16);
        if(lane < 32) As[row*168 + 128 + lane] = f2bf((xe-smu)*ssc*gs2 + bs2);
        unsigned short z0 = f2bf((dx0-dmu)*dsc*gd01.x + bd01.x);
        unsigned short z1 = f2bf((dx1-dmu)*dsc*gd01.y + bd01.y);
        ad_pair[lane] = (unsigned)z0 | ((unsigned)z1 << 16);
      } else {
        as_pair[lane] = 0u;
        if(lane < 32) As[row*168 + 128 + lane] = 0;
        ad_pair[lane] = 0u;
      }
    }
  }
  __syncthreads();                         // A tiles ready; no more barriers

  f32x4 q[8], kk[8], vv[8];
  gemm64r<4>(Ad, 136, Wq_t + r*16384, q,  tid);
  gemm64r<5>(As, 168, Wk_t + r*20480, kk, tid);
  // a[row][head] = sum over 16 cols of head-tile of q*k / sqrt(128)
  const float inv = 0.08838834764831845f;
  #pragma unroll
  for(int rt=0; rt<4; rt++)
  #pragma unroll
  for(int ct=0; ct<2; ct++){
    #pragma unroll
    for(int reg=0; reg<4; reg++){
      float s = q[rt*2+ct][reg] * kk[rt*2+ct][reg];
      s += __shfl_xor(s,1); s += __shfl_xor(s,2); s += __shfl_xor(s,4); s += __shfl_xor(s,8);
      int row = rt*16 + quad*4 + reg;
      if(m == 0 && row < nv) abuf[(size_t)(row0+row)*8 + w*2 + ct] = s * inv;
    }
  }
  gemm64r<5>(As, 168, Wv_t + r*20480, vv, tid);
  #pragma unroll
  for(int rt=0; rt<4; rt++)
  #pragma unroll
  for(int ct=0; ct<2; ct++)
  #pragma unroll
  for(int reg=0; reg<4; reg++){
    int row = rt*16 + quad*4 + reg;
    if(row < nv)
      vbuf[(size_t)(row0+row)*128 + w*32 + ct*16 + m] = f2bf(vv[rt*2+ct][reg]);
  }
}

// ---------------- per-dst softmax + weighted aggregate (no global atomics)
__global__ __launch_bounds__(128) void k_aggr(
  const float* __restrict__ abuf, const unsigned short* __restrict__ vbuf,
  const int* __restrict__ dstlist, const int* __restrict__ off_d,
  const int* __restrict__ npos, const int* __restrict__ ntype,
  const float* __restrict__ h_bias, unsigned short* __restrict__ hpre)
{
  int d = blockIdx.x, tid = threadIdx.x;
  int o0 = off_d[d], cnt = off_d[d+1] - o0;
  __shared__ float den[8];
  if(tid < 8) den[tid] = 0.f;
  __syncthreads();
  for(int idx = tid; idx < cnt*8; idx += 128){
    int i = idx >> 3, h = idx & 7;
    float ex = __expf(abuf[(size_t)dstlist[o0+i]*8 + h]);
    atomicAdd(&den[h], ex);
  }
  __syncthreads();
  int h = tid >> 4;
  float dh = den[h];
  float rd = (dh > 0.f) ? (1.f/dh) : 0.f;
  float acc = 0.f;
  for(int i=0; i<cnt; i++){
    int p = dstlist[o0+i];
    float al = __expf(abuf[(size_t)p*8 + h]) * rd;
    acc += al * bf2f(vbuf[(size_t)p*128 + tid]);
  }
  int t = ntype[d];
  acc += h_bias[t*128 + tid];
  hpre[(size_t)npos[d]*128 + tid] = f2bf(acc);   // write at ntype-sorted row
}

// ---------------- final typed GEMM (Wa) + gate + residual
__global__ __launch_bounds__(256) void k_final(
  const unsigned short* __restrict__ hpre, const unsigned short* __restrict__ Wa_t,
  const int* __restrict__ cnt_n, const int* __restrict__ off_n, const int* __restrict__ nperm,
  const float* __restrict__ skip, const float* __restrict__ src_h, float* __restrict__ out)
{
  __shared__ unsigned short Ah[64*136];
  int bid = blockIdx.x;
  int r = -1, tl0 = 0, accT = 0;
  #pragma unroll
  for(int i=0;i<4;i++){
    int n = cnt_n[i], tt = (n + 63) >> 6;
    if(r < 0 && bid < accT + tt){ r = i; tl0 = bid - accT; }
    accT += tt;
  }
  if(r < 0) return;
  int row0 = off_n[r] + tl0*64;
  int nv = min(64, cnt_n[r] - tl0*64);
  float gate = 1.f / (1.f + __expf(-skip[r]));
  int tid = threadIdx.x;
  int4 z = make_int4(0,0,0,0);
  #pragma unroll
  for(int it=0; it<4; it++){
    int idx = it*256 + tid, row = idx >> 4, c = idx & 15;
    int4 v = z;
    if(row < nv) v = *(const int4*)(hpre + (size_t)(row0+row)*128 + c*8);
    *(int4*)(Ah + row*136 + c*8) = v;
  }
  __syncthreads();
  f32x4 acc[8];
  gemm64r<4>(Ah, 136, Wa_t + r*16384, acc, tid);
  int lane = tid & 63, w = tid >> 6, m = lane & 15, quad = lane >> 4;
  #pragma unroll
  for(int rt=0; rt<4; rt++)
  #pragma unroll
  for(int ct=0; ct<2; ct++)
  #pragma unroll
  for(int reg=0; reg<4; reg++){
    int row = rt*16 + quad*4 + reg;
    if(row < nv){
      int dd = nperm[row0+row];
      int col = w*32 + ct*16 + m;
      out[(size_t)dd*128 + col] = acc[rt*2+ct][reg]*gate + src_h[(size_t)dd*128 + col]*(1.f - gate);
    }
  }
}

// ---------------------------------------------------------------------------
extern "C" void kernel_launch(void* const* d_in, const int* in_sizes, int n_in,
                              void* d_out, int out_size, void* d_ws, size_t ws_size,
                              hipStream_t stream)
{
  const float* src_h  = (const float*)d_in[0];
  const float* src_tw = (const float*)d_in[1];
  const float* src_tb = (const float*)d_in[2];
  const float* edge_h = (const float*)d_in[3];
  const float* date   = (const float*)d_in[4];
  const int*   src_idx= (const int*)d_in[5];
  const int*   dst_idx= (const int*)d_in[6];
  const int*   etype  = (const int*)d_in[7];
  const int*   ntype  = (const int*)d_in[8];
  const float* Wq     = (const float*)d_in[9];
  const float* Wk     = (const float*)d_in[10];
  const float* Wv     = (const float*)d_in[11];
  const float* Wa     = (const float*)d_in[12];
  const float* h_bias = (const float*)d_in[13];
  const float* skip   = (const float*)d_in[14];
  const float* g_s    = (const float*)d_in[15];
  const float* b_s    = (const float*)d_in[16];
  const float* g_d    = (const float*)d_in[17];
  const float* b_d    = (const float*)d_in[18];
  float* out = (float*)d_out;

  const int E = in_sizes[4];   // date
  const int M = in_sizes[8];   // ntype

  char* base = (char*)d_ws;
  size_t off = 0;
  auto alloc = [&](size_t bytes)->char*{
    off = (off + 255) & ~(size_t)255;
    char* p = base + off; off += bytes; return p;
  };
  // contiguous zero region: cnt_e[8] cur_e[8] cnt_n[4] cur_n[4] cnt_d[M] cur_d[M]
  int* cnt_e = (int*)alloc((size_t)(24 + 2*M)*4);
  int* cur_e = cnt_e + 8;
  int* cnt_n = cur_e + 8;
  int* cur_n = cnt_n + 4;
  int* cnt_d = cur_n + 4;
  int* cur_d = cnt_d + M;
  const int nzero = 24 + 2*M;
  int* off_e = (int*)alloc(9*4);
  int* off_n = (int*)alloc(5*4);
  int* off_d = (int*)alloc((size_t)(M+1)*4);
  int* eperm   = (int*)alloc((size_t)E*4);
  int* dstlist = (int*)alloc((size_t)E*4);
  int* nperm   = (int*)alloc((size_t)M*4);
  int* npos    = (int*)alloc((size_t)M*4);
  unsigned short* Wq_t = (unsigned short*)alloc((size_t)8*128*128*2);
  unsigned short* Wk_t = (unsigned short*)alloc((size_t)8*160*128*2);
  unsigned short* Wv_t = (unsigned short*)alloc((size_t)8*160*128*2);
  unsigned short* Wa_t = (unsigned short*)alloc((size_t)4*128*128*2);
  unsigned short* vbuf  = (unsigned short*)alloc((size_t)E*128*2);
  unsigned short* hpre  = (unsigned short*)alloc((size_t)M*128*2);
  float* abuf = (float*)alloc((size_t)E*8*4);

  k_zero<<<dim3((nzero+255)/256), dim3(256), 0, stream>>>(cnt_e, nzero);
  k_hist<<<dim3((E+255)/256), dim3(256), 0, stream>>>(etype, dst_idx, ntype, cnt_e, cnt_d, cnt_n, E, M);
  k_scan<<<dim3(1), dim3(1024), 0, stream>>>(cnt_e, off_e, cnt_n, off_n, cnt_d, off_d, M);
  k_scatter<<<dim3((E+255)/256), dim3(256), 0, stream>>>(etype, dst_idx, ntype,
      off_e, cur_e, off_d, cur_d, off_n, cur_n, eperm, dstlist, nperm, npos, E, M);
  k_convw<<<dim3(2048), dim3(256), 0, stream>>>(Wq, Wk, Wv, Wa, Wq_t, Wk_t, Wv_t, Wa_t);
  k_qkv<<<dim3(E/64 + 9), dim3(256), 0, stream>>>(src_h, src_tw, src_tb, edge_h, date,
      src_idx, dst_idx, eperm, g_s, b_s, g_d, b_d,
      Wq_t, Wk_t, Wv_t, cnt_e, off_e, abuf, vbuf);
  k_aggr<<<dim3(M), dim3(128), 0, stream>>>(abuf, vbuf, dstlist, off_d, npos, ntype, h_bias, hpre);
  k_final<<<dim3(M/64 + 5), dim3(256), 0, stream>>>(hpre, Wa_t, cnt_n, off_n, nperm, skip, src_h, out);
}

// Round 3
// 269.037 us; speedup vs baseline: 1.1564x; 1.1564x over previous
//
#include <hip/hip_runtime.h>

// ---------------------------------------------------------------------------
// HTGT layer: sort-by-type + bf16 MFMA pipeline
// dims (fixed by problem): N=50000 M=10000 E=100000, in=128 e=32 out=128 td=32
// R=8 etypes, T=4 ntypes, H=8 heads, hs=16
// R2: k_hist/k_scatter hot-counter atomics hierarchized
// R3: register-resident-B GEMMs (fragment-major weights, no Bt LDS staging)
// R4 (REVERTED): prep-into-qkv fusion dropped occupancy 76%->18% on the
//     gather chain -> latency-bound, 2.6x slower. Keep prep separate.
// R5: k_prep rewritten: 2 edges/wave (32 lanes each, shfl_xor<32 stays in
//     group), single-pass sum/sumsq LN (4 independent butterflies), float4
//     gathers + packed bf16x2 stores. ~2.5x fewer VALU ops/edge, 10 vs 24
//     shuffle ops/edge. VGPR stays low -> occupancy stays ~75%.
// ---------------------------------------------------------------------------

typedef __attribute__((ext_vector_type(8))) short short8;
typedef __attribute__((ext_vector_type(4))) float f32x4;

__device__ __forceinline__ unsigned short f2bf(float f){
  union { float f; unsigned u; } x; x.f = f;
  unsigned r = x.u + 0x7FFFu + ((x.u >> 16) & 1u);
  return (unsigned short)(r >> 16);
}
__device__ __forceinline__ float bf2f(unsigned short b){
  union { unsigned u; float f; } x; x.u = ((unsigned)b) << 16;
  return x.f;
}

// ---------------- setup kernels ----------------

__global__ void k_zero(int* __restrict__ p, int n){
  int i = blockIdx.x*256 + threadIdx.x;
  if(i < n) p[i] = 0;
}

__global__ __launch_bounds__(256) void k_hist(
    const int* __restrict__ etype, const int* __restrict__ dst_idx,
    const int* __restrict__ ntype,
    int* cnt_e, int* cnt_d, int* cnt_n, int E, int M){
  __shared__ int le[8], ln[4];
  int tid = threadIdx.x;
  if(tid < 8) le[tid] = 0;
  if(tid < 4) ln[tid] = 0;
  __syncthreads();
  int g = blockIdx.x*256 + tid;
  if(g < E){ atomicAdd(&le[etype[g]], 1); atomicAdd(&cnt_d[dst_idx[g]], 1); }
  if(g < M){ atomicAdd(&ln[ntype[g]], 1); }
  __syncthreads();
  if(tid < 8 && le[tid]) atomicAdd(&cnt_e[tid], le[tid]);
  if(tid < 4 && ln[tid]) atomicAdd(&cnt_n[tid], ln[tid]);
}

__global__ __launch_bounds__(1024) void k_scan(const int* __restrict__ cnt_e, int* off_e,
                                               const int* __restrict__ cnt_n, int* off_n,
                                               const int* __restrict__ cnt_d, int* off_d, int M){
  __shared__ int part[1024];
  int tid = threadIdx.x;
  if(tid == 0){
    int s = 0;
    for(int i=0;i<8;i++){ off_e[i]=s; s+=cnt_e[i]; } off_e[8]=s;
    s = 0;
    for(int i=0;i<4;i++){ off_n[i]=s; s+=cnt_n[i]; } off_n[4]=s;
  }
  int per = (M + 1023) >> 10;
  int s = 0;
  for(int j=0;j<per;j++){ int idx = tid*per + j; if(idx < M) s += cnt_d[idx]; }
  part[tid] = s; __syncthreads();
  for(int o=1;o<1024;o<<=1){
    int v = (tid >= o) ? part[tid-o] : 0;
    __syncthreads();
    part[tid] += v;
    __syncthreads();
  }
  int run = (tid == 0) ? 0 : part[tid-1];
  for(int j=0;j<per;j++){
    int idx = tid*per + j;
    if(idx < M){ off_d[idx] = run; run += cnt_d[idx]; }
  }
  if(tid == 1023) off_d[M] = run;
}

__global__ __launch_bounds__(256) void k_scatter(
    const int* __restrict__ etype, const int* __restrict__ dst_idx,
    const int* __restrict__ ntype,
    const int* __restrict__ off_e, int* cur_e,
    const int* __restrict__ off_d, int* cur_d,
    const int* __restrict__ off_n, int* cur_n,
    int* eperm, int* dstlist, int* nperm, int* npos, int E, int M){
  __shared__ int lcnt[8], lbase[8], lnc[4], lnb[4];
  int tid = threadIdx.x;
  if(tid < 8) lcnt[tid] = 0;
  if(tid < 4) lnc[tid] = 0;
  __syncthreads();
  int g = blockIdx.x*256 + tid;
  int r = 0, lrank = 0, t = 0, nrank = 0;
  bool inE = (g < E), inM = (g < M);
  if(inE){ r = etype[g]; lrank = atomicAdd(&lcnt[r], 1); }
  if(inM){ t = ntype[g]; nrank = atomicAdd(&lnc[t], 1); }
  __syncthreads();
  if(tid < 8 && lcnt[tid]) lbase[tid] = atomicAdd(&cur_e[tid], lcnt[tid]);
  if(tid < 4 && lnc[tid])  lnb[tid]   = atomicAdd(&cur_n[tid], lnc[tid]);
  __syncthreads();
  if(inE){
    int p = off_e[r] + lbase[r] + lrank;
    eperm[p] = g;
    int d = dst_idx[g];
    int q = off_d[d] + atomicAdd(&cur_d[d], 1);   // ~10-way contention, benign
    dstlist[q] = p;                               // etype-sorted position
  }
  if(inM){
    int np = off_n[t] + lnb[t] + nrank;
    npos[g] = np;
    nperm[np] = g;
  }
}

// convert weights to bf16 FRAGMENT-MAJOR layout:
//   [r][nb][c][quad][m][j]  (n = nb*16+m = out col, k = c*32+quad*8+j = in dim)
// so that wave w's B-fragment for chunk c is one contiguous, coalesced 1KB
// block: lane l (l = quad*16+m) reads 16B at block_base + l*16.
__global__ void k_convw(const float* __restrict__ Wq, const float* __restrict__ Wk,
                        const float* __restrict__ Wv, const float* __restrict__ Wa,
                        unsigned short* Wq_t, unsigned short* Wk_t,
                        unsigned short* Wv_t, unsigned short* Wa_t){
  int tid = blockIdx.x*256 + threadIdx.x;
  if(tid < 131072){                                  // Wq: 8 x 128(k) x 128(n)
    int r = tid >> 14, rem = tid & 16383, k = rem >> 7, n = rem & 127;
    int nb=n>>4, m=n&15, c=k>>5, quad=(k>>3)&3, j=k&7;
    Wq_t[r*16384 + ((nb*4 + c)*4 + quad)*128 + m*8 + j] = f2bf(Wq[tid]);
  } else if(tid < 294912){                           // Wk: 8 x 160(k) x 128(n)
    int u = tid - 131072;
    int r = u / 20480, rem = u - r*20480, k = rem >> 7, n = rem & 127;
    int nb=n>>4, m=n&15, c=k>>5, quad=(k>>3)&3, j=k&7;
    Wk_t[r*20480 + ((nb*5 + c)*4 + quad)*128 + m*8 + j] = f2bf(Wk[u]);
  } else if(tid < 458752){                           // Wv: 8 x 160(k) x 128(n)
    int u = tid - 294912;
    int r = u / 20480, rem = u - r*20480, k = rem >> 7, n = rem & 127;
    int nb=n>>4, m=n&15, c=k>>5, quad=(k>>3)&3, j=k&7;
    Wv_t[r*20480 + ((nb*5 + c)*4 + quad)*128 + m*8 + j] = f2bf(Wv[u]);
  } else if(tid < 524288){                           // Wa: 4 x 128(k) x 128(n)
    int u = tid - 458752;
    int r = u >> 14, rem = u & 16383, k = rem >> 7, n = rem & 127;
    int nb=n>>4, m=n&15, c=k>>5, quad=(k>>3)&3, j=k&7;
    Wa_t[r*16384 + ((nb*4 + c)*4 + quad)*128 + m*8 + j] = f2bf(Wa[u]);
  }
}

// ---------------- prep: gather + temporal encode + LN, etype-sorted order
// 2 edges per wave: lanes 0-31 edge A, lanes 32-63 edge B (shfl_xor<32 stays
// within group). Lane l covers elems 4l..4l+3 (float4) + edge elem l.
// Single-pass LN: var = E[x^2]-mu^2; 4 independent butterflies.
__global__ __launch_bounds__(256) void k_prep(
  const float* __restrict__ src_h, const float* __restrict__ src_tw, const float* __restrict__ src_tb,
  const float* __restrict__ edge_h, const float* __restrict__ date,
  const int* __restrict__ src_idx, const int* __restrict__ dst_idx, const int* __restrict__ eperm,
  const float* __restrict__ g_s, const float* __restrict__ b_s,
  const float* __restrict__ g_d, const float* __restrict__ b_d,
  unsigned short* __restrict__ dia_s, unsigned short* __restrict__ dia_d, int E)
{
  int p = blockIdx.x*8 + (threadIdx.x >> 5);
  if(p >= E) return;
  int l = threadIdx.x & 31;
  int e = eperm[p];
  float t = date[e];
  int s = src_idx[e], d = dst_idx[e];
  float4 hs = *(const float4*)(src_h + (size_t)s*128 + 4*l);
  float4 hd = *(const float4*)(src_h + (size_t)d*128 + 4*l);
  float xe = edge_h[(size_t)e*32 + l];
  float4 sx = hs, dx = hd;
  if(l < 8){                                 // elems 0..31 get temporal encode
    float4 w4, c4;
    w4 = *(const float4*)(src_tw + (size_t)s*32 + 4*l);
    c4 = *(const float4*)(src_tb + (size_t)s*32 + 4*l);
    sx.x = __sinf(w4.x*t + c4.x) * hs.x;
    sx.y = __sinf(w4.y*t + c4.y) * hs.y;
    sx.z = __sinf(w4.z*t + c4.z) * hs.z;
    sx.w = __sinf(w4.w*t + c4.w) * hs.w;
    w4 = *(const float4*)(src_tw + (size_t)d*32 + 4*l);
    c4 = *(const float4*)(src_tb + (size_t)d*32 + 4*l);
    dx.x = __sinf(w4.x*t + c4.x) * hd.x;
    dx.y = __sinf(w4.y*t + c4.y) * hd.y;
    dx.z = __sinf(w4.z*t + c4.z) * hd.z;
    dx.w = __sinf(w4.w*t + c4.w) * hd.w;
  }
  float s1 = sx.x + sx.y + sx.z + sx.w + xe;
  float s2 = sx.x*sx.x + sx.y*sx.y + sx.z*sx.z + sx.w*sx.w + xe*xe;
  float t1 = dx.x + dx.y + dx.z + dx.w;
  float t2 = dx.x*dx.x + dx.y*dx.y + dx.z*dx.z + dx.w*dx.w;
  #pragma unroll
  for(int i=1;i<32;i<<=1){
    s1 += __shfl_xor(s1,i); s2 += __shfl_xor(s2,i);
    t1 += __shfl_xor(t1,i); t2 += __shfl_xor(t2,i);
  }
  float smu = s1*(1.f/160.f);
  float ssc = rsqrtf(s2*(1.f/160.f) - smu*smu + 1e-5f);
  float dmu = t1*(1.f/128.f);
  float dsc = rsqrtf(t2*(1.f/128.f) - dmu*dmu + 1e-5f);
  float4 gs = *(const float4*)(g_s + 4*l), bs = *(const float4*)(b_s + 4*l);
  float4 gd = *(const float4*)(g_d + 4*l), bd = *(const float4*)(b_d + 4*l);
  unsigned r0 = (unsigned)f2bf((sx.x-smu)*ssc*gs.x + bs.x)
              | ((unsigned)f2bf((sx.y-smu)*ssc*gs.y + bs.y) << 16);
  unsigned r1 = (unsigned)f2bf((sx.z-smu)*ssc*gs.z + bs.z)
              | ((unsigned)f2bf((sx.w-smu)*ssc*gs.w + bs.w) << 16);
  uint2 rs; rs.x = r0; rs.y = r1;
  *(uint2*)(dia_s + (size_t)p*160 + 4*l) = rs;
  dia_s[(size_t)p*160 + 128 + l] = f2bf((xe-smu)*ssc*g_s[128+l] + b_s[128+l]);
  unsigned d0 = (unsigned)f2bf((dx.x-dmu)*dsc*gd.x + bd.x)
              | ((unsigned)f2bf((dx.y-dmu)*dsc*gd.y + bd.y) << 16);
  unsigned d1 = (unsigned)f2bf((dx.z-dmu)*dsc*gd.z + bd.z)
              | ((unsigned)f2bf((dx.w-dmu)*dsc*gd.w + bd.w) << 16);
  uint2 rd; rd.x = d0; rd.y = d1;
  *(uint2*)(dia_d + (size_t)p*128 + 4*l) = rd;
}

// ---------------- shared GEMM core: 64 rows x 128 cols, wave = 64 rows x 32 cols
// A in LDS [64][lda] bf16 (staged + synced by caller, read-only here);
// Wf global bf16 in fragment-major layout; B lives in registers, no barriers.
template<int NC>
__device__ __forceinline__ void gemm64r(
  const unsigned short* __restrict__ A, int lda,
  const unsigned short* __restrict__ Wf,
  f32x4* acc, int tid)
{
  int lane = tid & 63, w = tid >> 6, m = lane & 15, quad = lane >> 4;
  // per-wave B fragments: nb=2w (cols w*32..w*32+15), nb=2w+1 (cols +16..+31)
  const unsigned short* p0 = Wf + (size_t)(2*w)*NC*512 + lane*8;
  short8 b0[NC], b1[NC];
  #pragma unroll
  for(int c=0;c<NC;c++){
    b0[c] = *(const short8*)(p0 + c*512);
    b1[c] = *(const short8*)(p0 + NC*512 + c*512);
  }
  #pragma unroll
  for(int i=0;i<8;i++) acc[i] = (f32x4){0.f,0.f,0.f,0.f};
  #pragma unroll
  for(int c=0;c<NC;c++){
    #pragma unroll
    for(int rt=0; rt<4; rt++){
      short8 af = *(const short8*)(A + (rt*16 + m)*lda + c*32 + quad*8);
      acc[rt*2+0] = __builtin_amdgcn_mfma_f32_16x16x32_bf16(af, b0[c], acc[rt*2+0], 0,0,0);
      acc[rt*2+1] = __builtin_amdgcn_mfma_f32_16x16x32_bf16(af, b1[c], acc[rt*2+1], 0,0,0);
    }
  }
}

// ---------------- fused typed q/k/v GEMM + attention scores
__global__ __launch_bounds__(256) void k_qkv(
  const unsigned short* __restrict__ dia_d, const unsigned short* __restrict__ dia_s,
  const unsigned short* __restrict__ Wq_t, const unsigned short* __restrict__ Wk_t,
  const unsigned short* __restrict__ Wv_t,
  const int* __restrict__ cnt_e, const int* __restrict__ off_e,
  float* __restrict__ abuf, unsigned short* __restrict__ vbuf)
{
  __shared__ unsigned short Ad[64*136];
  __shared__ unsigned short As[64*168];
  int bid = blockIdx.x;
  int r = -1, tl0 = 0, accT = 0;
  #pragma unroll
  for(int i=0;i<8;i++){
    int n = cnt_e[i], tt = (n + 63) >> 6;
    if(r < 0 && bid < accT + tt){ r = i; tl0 = bid - accT; }
    accT += tt;
  }
  if(r < 0) return;
  int row0 = off_e[r] + tl0*64;
  int nv = min(64, cnt_e[r] - tl0*64);
  int tid = threadIdx.x;
  {
    int4 z = make_int4(0,0,0,0);
    #pragma unroll
    for(int it=0; it<4; it++){            // stage dia_d tile
      int idx = it*256 + tid, row = idx >> 4, c = idx & 15;
      int4 v = z;
      if(row < nv) v = *(const int4*)(dia_d + (size_t)(row0+row)*128 + c*8);
      *(int4*)(Ad + row*136 + c*8) = v;
    }
    #pragma unroll
    for(int it=0; it<5; it++){            // stage dia_s tile
      int idx = it*256 + tid, row = idx/20, c = idx%20;
      int4 v = z;
      if(row < nv) v = *(const int4*)(dia_s + (size_t)(row0+row)*160 + c*8);
      *(int4*)(As + row*168 + c*8) = v;
    }
  }
  __syncthreads();                         // A tiles ready; no more barriers
  int lane = tid & 63, w = tid >> 6, m = lane & 15, quad = lane >> 4;
  f32x4 q[8], kk[8], vv[8];
  gemm64r<4>(Ad, 136, Wq_t + r*16384, q,  tid);
  gemm64r<5>(As, 168, Wk_t + r*20480, kk, tid);
  // a[row][head] = sum over 16 cols of head-tile of q*k / sqrt(128)
  const float inv = 0.08838834764831845f;
  #pragma unroll
  for(int rt=0; rt<4; rt++)
  #pragma unroll
  for(int ct=0; ct<2; ct++){
    #pragma unroll
    for(int reg=0; reg<4; reg++){
      float s = q[rt*2+ct][reg] * kk[rt*2+ct][reg];
      s += __shfl_xor(s,1); s += __shfl_xor(s,2); s += __shfl_xor(s,4); s += __shfl_xor(s,8);
      int row = rt*16 + quad*4 + reg;
      if(m == 0 && row < nv) abuf[(size_t)(row0+row)*8 + w*2 + ct] = s * inv;
    }
  }
  gemm64r<5>(As, 168, Wv_t + r*20480, vv, tid);
  #pragma unroll
  for(int rt=0; rt<4; rt++)
  #pragma unroll
  for(int ct=0; ct<2; ct++)
  #pragma unroll
  for(int reg=0; reg<4; reg++){
    int row = rt*16 + quad*4 + reg;
    if(row < nv)
      vbuf[(size_t)(row0+row)*128 + w*32 + ct*16 + m] = f2bf(vv[rt*2+ct][reg]);
  }
}

// ---------------- per-dst softmax + weighted aggregate (no global atomics)
__global__ __launch_bounds__(128) void k_aggr(
  const float* __restrict__ abuf, const unsigned short* __restrict__ vbuf,
  const int* __restrict__ dstlist, const int* __restrict__ off_d,
  const int* __restrict__ npos, const int* __restrict__ ntype,
  const float* __restrict__ h_bias, unsigned short* __restrict__ hpre)
{
  int d = blockIdx.x, tid = threadIdx.x;
  int o0 = off_d[d], cnt = off_d[d+1] - o0;
  __shared__ float den[8];
  if(tid < 8) den[tid] = 0.f;
  __syncthreads();
  for(int idx = tid; idx < cnt*8; idx += 128){
    int i = idx >> 3, h = idx & 7;
    float ex = __expf(abuf[(size_t)dstlist[o0+i]*8 + h]);
    atomicAdd(&den[h], ex);
  }
  __syncthreads();
  int h = tid >> 4;
  float dh = den[h];
  float rd = (dh > 0.f) ? (1.f/dh) : 0.f;
  float acc = 0.f;
  for(int i=0; i<cnt; i++){
    int p = dstlist[o0+i];
    float al = __expf(abuf[(size_t)p*8 + h]) * rd;
    acc += al * bf2f(vbuf[(size_t)p*128 + tid]);
  }
  int t = ntype[d];
  acc += h_bias[t*128 + tid];
  hpre[(size_t)npos[d]*128 + tid] = f2bf(acc);   // write at ntype-sorted row
}

// ---------------- final typed GEMM (Wa) + gate + residual
__global__ __launch_bounds__(256) void k_final(
  const unsigned short* __restrict__ hpre, const unsigned short* __restrict__ Wa_t,
  const int* __restrict__ cnt_n, const int* __restrict__ off_n, const int* __restrict__ nperm,
  const float* __restrict__ skip, const float* __restrict__ src_h, float* __restrict__ out)
{
  __shared__ unsigned short Ah[64*136];
  int bid = blockIdx.x;
  int r = -1, tl0 = 0, accT = 0;
  #pragma unroll
  for(int i=0;i<4;i++){
    int n = cnt_n[i], tt = (n + 63) >> 6;
    if(r < 0 && bid < accT + tt){ r = i; tl0 = bid - accT; }
    accT += tt;
  }
  if(r < 0) return;
  int row0 = off_n[r] + tl0*64;
  int nv = min(64, cnt_n[r] - tl0*64);
  float gate = 1.f / (1.f + __expf(-skip[r]));
  int tid = threadIdx.x;
  int4 z = make_int4(0,0,0,0);
  #pragma unroll
  for(int it=0; it<4; it++){
    int idx = it*256 + tid, row = idx >> 4, c = idx & 15;
    int4 v = z;
    if(row < nv) v = *(const int4*)(hpre + (size_t)(row0+row)*128 + c*8);
    *(int4*)(Ah + row*136 + c*8) = v;
  }
  __syncthreads();
  f32x4 acc[8];
  gemm64r<4>(Ah, 136, Wa_t + r*16384, acc, tid);
  int lane = tid & 63, w = tid >> 6, m = lane & 15, quad = lane >> 4;
  #pragma unroll
  for(int rt=0; rt<4; rt++)
  #pragma unroll
  for(int ct=0; ct<2; ct++)
  #pragma unroll
  for(int reg=0; reg<4; reg++){
    int row = rt*16 + quad*4 + reg;
    if(row < nv){
      int dd = nperm[row0+row];
      int col = w*32 + ct*16 + m;
      out[(size_t)dd*128 + col] = acc[rt*2+ct][reg]*gate + src_h[(size_t)dd*128 + col]*(1.f - gate);
    }
  }
}

// ---------------------------------------------------------------------------
extern "C" void kernel_launch(void* const* d_in, const int* in_sizes, int n_in,
                              void* d_out, int out_size, void* d_ws, size_t ws_size,
                              hipStream_t stream)
{
  const float* src_h  = (const float*)d_in[0];
  const float* src_tw = (const float*)d_in[1];
  const float* src_tb = (const float*)d_in[2];
  const float* edge_h = (const float*)d_in[3];
  const float* date   = (const float*)d_in[4];
  const int*   src_idx= (const int*)d_in[5];
  const int*   dst_idx= (const int*)d_in[6];
  const int*   etype  = (const int*)d_in[7];
  const int*   ntype  = (const int*)d_in[8];
  const float* Wq     = (const float*)d_in[9];
  const float* Wk     = (const float*)d_in[10];
  const float* Wv     = (const float*)d_in[11];
  const float* Wa     = (const float*)d_in[12];
  const float* h_bias = (const float*)d_in[13];
  const float* skip   = (const float*)d_in[14];
  const float* g_s    = (const float*)d_in[15];
  const float* b_s    = (const float*)d_in[16];
  const float* g_d    = (const float*)d_in[17];
  const float* b_d    = (const float*)d_in[18];
  float* out = (float*)d_out;

  const int E = in_sizes[4];   // date
  const int M = in_sizes[8];   // ntype

  char* base = (char*)d_ws;
  size_t off = 0;
  auto alloc = [&](size_t bytes)->char*{
    off = (off + 255) & ~(size_t)255;
    char* p = base + off; off += bytes; return p;
  };
  // contiguous zero region: cnt_e[8] cur_e[8] cnt_n[4] cur_n[4] cnt_d[M] cur_d[M]
  int* cnt_e = (int*)alloc((size_t)(24 + 2*M)*4);
  int* cur_e = cnt_e + 8;
  int* cnt_n = cur_e + 8;
  int* cur_n = cnt_n + 4;
  int* cnt_d = cur_n + 4;
  int* cur_d = cnt_d + M;
  const int nzero = 24 + 2*M;
  int* off_e = (int*)alloc(9*4);
  int* off_n = (int*)alloc(5*4);
  int* off_d = (int*)alloc((size_t)(M+1)*4);
  int* eperm   = (int*)alloc((size_t)E*4);
  int* dstlist = (int*)alloc((size_t)E*4);
  int* nperm   = (int*)alloc((size_t)M*4);
  int* npos    = (int*)alloc((size_t)M*4);
  unsigned short* Wq_t = (unsigned short*)alloc((size_t)8*128*128*2);
  unsigned short* Wk_t = (unsigned short*)alloc((size_t)8*160*128*2);
  unsigned short* Wv_t = (unsigned short*)alloc((size_t)8*160*128*2);
  unsigned short* Wa_t = (unsigned short*)alloc((size_t)4*128*128*2);
  unsigned short* dia_d = (unsigned short*)alloc((size_t)E*128*2);
  unsigned short* dia_s = (unsigned short*)alloc((size_t)E*160*2);
  unsigned short* vbuf  = (unsigned short*)alloc((size_t)E*128*2);
  unsigned short* hpre  = (unsigned short*)alloc((size_t)M*128*2);
  float* abuf = (float*)alloc((size_t)E*8*4);

  k_zero<<<dim3((nzero+255)/256), dim3(256), 0, stream>>>(cnt_e, nzero);
  k_hist<<<dim3((E+255)/256), dim3(256), 0, stream>>>(etype, dst_idx, ntype, cnt_e, cnt_d, cnt_n, E, M);
  k_scan<<<dim3(1), dim3(1024), 0, stream>>>(cnt_e, off_e, cnt_n, off_n, cnt_d, off_d, M);
  k_scatter<<<dim3((E+255)/256), dim3(256), 0, stream>>>(etype, dst_idx, ntype,
      off_e, cur_e, off_d, cur_d, off_n, cur_n, eperm, dstlist, nperm, npos, E, M);
  k_convw<<<dim3(2048), dim3(256), 0, stream>>>(Wq, Wk, Wv, Wa, Wq_t, Wk_t, Wv_t, Wa_t);
  k_prep<<<dim3((E+7)/8), dim3(256), 0, stream>>>(src_h, src_tw, src_tb, edge_h, date,
      src_idx, dst_idx, eperm, g_s, b_s, g_d, b_d, dia_s, dia_d, E);
  k_qkv<<<dim3(E/64 + 9), dim3(256), 0, stream>>>(dia_d, dia_s, Wq_t, Wk_t, Wv_t,
      cnt_e, off_e, abuf, vbuf);
  k_aggr<<<dim3(M), dim3(128), 0, stream>>>(abuf, vbuf, dstlist, off_d, npos, ntype, h_bias, hpre);
  k_final<<<dim3(M/64 + 5), dim3(256), 0, stream>>>(hpre, Wa_t, cnt_n, off_n, nperm, skip, src_h, out);
}

// Round 4
// 264.594 us; speedup vs baseline: 1.1758x; 1.0168x over previous
//
#include <hip/hip_runtime.h>

// ---------------------------------------------------------------------------
// HTGT layer: sort-by-type + bf16 MFMA pipeline
// dims (fixed by problem): N=50000 M=10000 E=100000, in=128 e=32 out=128 td=32
// R=8 etypes, T=4 ntypes, H=8 heads, hs=16
// R2: k_hist/k_scatter hot-counter atomics hierarchized
// R3: register-resident-B GEMMs (fragment-major weights, no Bt LDS staging)
// R4 (REVERTED): prep-into-qkv fusion -> occupancy collapse on gather chain
// R5: k_prep 2 edges/wave, single-pass LN, float4 gathers
// R6: k_qkv/k_final go 8-wave (512 thr): wave w owns 16 cols (= head w).
//     Per-wave accs halve (q/kk/vv 4xf32x4 each), B-frags halve -> combined
//     VGPR+AGPR ~halves -> 2x+ waves/SIMD resident. Same 64-row tile, same
//     LDS, same fragment-major weights (nb = w). Attacks the 16% occupancy
//     latency-bound profile of R5's k_qkv (53us vs ~12us roofline).
// ---------------------------------------------------------------------------

typedef __attribute__((ext_vector_type(8))) short short8;
typedef __attribute__((ext_vector_type(4))) float f32x4;

__device__ __forceinline__ unsigned short f2bf(float f){
  union { float f; unsigned u; } x; x.f = f;
  unsigned r = x.u + 0x7FFFu + ((x.u >> 16) & 1u);
  return (unsigned short)(r >> 16);
}
__device__ __forceinline__ float bf2f(unsigned short b){
  union { unsigned u; float f; } x; x.u = ((unsigned)b) << 16;
  return x.f;
}

// ---------------- setup kernels ----------------

__global__ void k_zero(int* __restrict__ p, int n){
  int i = blockIdx.x*256 + threadIdx.x;
  if(i < n) p[i] = 0;
}

__global__ __launch_bounds__(256) void k_hist(
    const int* __restrict__ etype, const int* __restrict__ dst_idx,
    const int* __restrict__ ntype,
    int* cnt_e, int* cnt_d, int* cnt_n, int E, int M){
  __shared__ int le[8], ln[4];
  int tid = threadIdx.x;
  if(tid < 8) le[tid] = 0;
  if(tid < 4) ln[tid] = 0;
  __syncthreads();
  int g = blockIdx.x*256 + tid;
  if(g < E){ atomicAdd(&le[etype[g]], 1); atomicAdd(&cnt_d[dst_idx[g]], 1); }
  if(g < M){ atomicAdd(&ln[ntype[g]], 1); }
  __syncthreads();
  if(tid < 8 && le[tid]) atomicAdd(&cnt_e[tid], le[tid]);
  if(tid < 4 && ln[tid]) atomicAdd(&cnt_n[tid], ln[tid]);
}

__global__ __launch_bounds__(1024) void k_scan(const int* __restrict__ cnt_e, int* off_e,
                                               const int* __restrict__ cnt_n, int* off_n,
                                               const int* __restrict__ cnt_d, int* off_d, int M){
  __shared__ int part[1024];
  int tid = threadIdx.x;
  if(tid == 0){
    int s = 0;
    for(int i=0;i<8;i++){ off_e[i]=s; s+=cnt_e[i]; } off_e[8]=s;
    s = 0;
    for(int i=0;i<4;i++){ off_n[i]=s; s+=cnt_n[i]; } off_n[4]=s;
  }
  int per = (M + 1023) >> 10;
  int s = 0;
  for(int j=0;j<per;j++){ int idx = tid*per + j; if(idx < M) s += cnt_d[idx]; }
  part[tid] = s; __syncthreads();
  for(int o=1;o<1024;o<<=1){
    int v = (tid >= o) ? part[tid-o] : 0;
    __syncthreads();
    part[tid] += v;
    __syncthreads();
  }
  int run = (tid == 0) ? 0 : part[tid-1];
  for(int j=0;j<per;j++){
    int idx = tid*per + j;
    if(idx < M){ off_d[idx] = run; run += cnt_d[idx]; }
  }
  if(tid == 1023) off_d[M] = run;
}

__global__ __launch_bounds__(256) void k_scatter(
    const int* __restrict__ etype, const int* __restrict__ dst_idx,
    const int* __restrict__ ntype,
    const int* __restrict__ off_e, int* cur_e,
    const int* __restrict__ off_d, int* cur_d,
    const int* __restrict__ off_n, int* cur_n,
    int* eperm, int* dstlist, int* nperm, int* npos, int E, int M){
  __shared__ int lcnt[8], lbase[8], lnc[4], lnb[4];
  int tid = threadIdx.x;
  if(tid < 8) lcnt[tid] = 0;
  if(tid < 4) lnc[tid] = 0;
  __syncthreads();
  int g = blockIdx.x*256 + tid;
  int r = 0, lrank = 0, t = 0, nrank = 0;
  bool inE = (g < E), inM = (g < M);
  if(inE){ r = etype[g]; lrank = atomicAdd(&lcnt[r], 1); }
  if(inM){ t = ntype[g]; nrank = atomicAdd(&lnc[t], 1); }
  __syncthreads();
  if(tid < 8 && lcnt[tid]) lbase[tid] = atomicAdd(&cur_e[tid], lcnt[tid]);
  if(tid < 4 && lnc[tid])  lnb[tid]   = atomicAdd(&cur_n[tid], lnc[tid]);
  __syncthreads();
  if(inE){
    int p = off_e[r] + lbase[r] + lrank;
    eperm[p] = g;
    int d = dst_idx[g];
    int q = off_d[d] + atomicAdd(&cur_d[d], 1);   // ~10-way contention, benign
    dstlist[q] = p;                               // etype-sorted position
  }
  if(inM){
    int np = off_n[t] + lnb[t] + nrank;
    npos[g] = np;
    nperm[np] = g;
  }
}

// convert weights to bf16 FRAGMENT-MAJOR layout:
//   [r][nb][c][quad][m][j]  (n = nb*16+m = out col, k = c*32+quad*8+j = in dim)
// wave w's B-fragment for chunk c (nb=w) is one contiguous, coalesced 1KB
// block: lane l (l = quad*16+m) reads 16B at block_base + l*16.
__global__ void k_convw(const float* __restrict__ Wq, const float* __restrict__ Wk,
                        const float* __restrict__ Wv, const float* __restrict__ Wa,
                        unsigned short* Wq_t, unsigned short* Wk_t,
                        unsigned short* Wv_t, unsigned short* Wa_t){
  int tid = blockIdx.x*256 + threadIdx.x;
  if(tid < 131072){                                  // Wq: 8 x 128(k) x 128(n)
    int r = tid >> 14, rem = tid & 16383, k = rem >> 7, n = rem & 127;
    int nb=n>>4, m=n&15, c=k>>5, quad=(k>>3)&3, j=k&7;
    Wq_t[r*16384 + ((nb*4 + c)*4 + quad)*128 + m*8 + j] = f2bf(Wq[tid]);
  } else if(tid < 294912){                           // Wk: 8 x 160(k) x 128(n)
    int u = tid - 131072;
    int r = u / 20480, rem = u - r*20480, k = rem >> 7, n = rem & 127;
    int nb=n>>4, m=n&15, c=k>>5, quad=(k>>3)&3, j=k&7;
    Wk_t[r*20480 + ((nb*5 + c)*4 + quad)*128 + m*8 + j] = f2bf(Wk[u]);
  } else if(tid < 458752){                           // Wv: 8 x 160(k) x 128(n)
    int u = tid - 294912;
    int r = u / 20480, rem = u - r*20480, k = rem >> 7, n = rem & 127;
    int nb=n>>4, m=n&15, c=k>>5, quad=(k>>3)&3, j=k&7;
    Wv_t[r*20480 + ((nb*5 + c)*4 + quad)*128 + m*8 + j] = f2bf(Wv[u]);
  } else if(tid < 524288){                           // Wa: 4 x 128(k) x 128(n)
    int u = tid - 458752;
    int r = u >> 14, rem = u & 16383, k = rem >> 7, n = rem & 127;
    int nb=n>>4, m=n&15, c=k>>5, quad=(k>>3)&3, j=k&7;
    Wa_t[r*16384 + ((nb*4 + c)*4 + quad)*128 + m*8 + j] = f2bf(Wa[u]);
  }
}

// ---------------- prep: gather + temporal encode + LN, etype-sorted order
// 2 edges per wave: lanes 0-31 edge A, lanes 32-63 edge B (shfl_xor<32 stays
// within group). Lane l covers elems 4l..4l+3 (float4) + edge elem l.
// Single-pass LN: var = E[x^2]-mu^2; 4 independent butterflies.
__global__ __launch_bounds__(256) void k_prep(
  const float* __restrict__ src_h, const float* __restrict__ src_tw, const float* __restrict__ src_tb,
  const float* __restrict__ edge_h, const float* __restrict__ date,
  const int* __restrict__ src_idx, const int* __restrict__ dst_idx, const int* __restrict__ eperm,
  const float* __restrict__ g_s, const float* __restrict__ b_s,
  const float* __restrict__ g_d, const float* __restrict__ b_d,
  unsigned short* __restrict__ dia_s, unsigned short* __restrict__ dia_d, int E)
{
  int p = blockIdx.x*8 + (threadIdx.x >> 5);
  if(p >= E) return;
  int l = threadIdx.x & 31;
  int e = eperm[p];
  float t = date[e];
  int s = src_idx[e], d = dst_idx[e];
  float4 hs = *(const float4*)(src_h + (size_t)s*128 + 4*l);
  float4 hd = *(const float4*)(src_h + (size_t)d*128 + 4*l);
  float xe = edge_h[(size_t)e*32 + l];
  float4 sx = hs, dx = hd;
  if(l < 8){                                 // elems 0..31 get temporal encode
    float4 w4, c4;
    w4 = *(const float4*)(src_tw + (size_t)s*32 + 4*l);
    c4 = *(const float4*)(src_tb + (size_t)s*32 + 4*l);
    sx.x = __sinf(w4.x*t + c4.x) * hs.x;
    sx.y = __sinf(w4.y*t + c4.y) * hs.y;
    sx.z = __sinf(w4.z*t + c4.z) * hs.z;
    sx.w = __sinf(w4.w*t + c4.w) * hs.w;
    w4 = *(const float4*)(src_tw + (size_t)d*32 + 4*l);
    c4 = *(const float4*)(src_tb + (size_t)d*32 + 4*l);
    dx.x = __sinf(w4.x*t + c4.x) * hd.x;
    dx.y = __sinf(w4.y*t + c4.y) * hd.y;
    dx.z = __sinf(w4.z*t + c4.z) * hd.z;
    dx.w = __sinf(w4.w*t + c4.w) * hd.w;
  }
  float s1 = sx.x + sx.y + sx.z + sx.w + xe;
  float s2 = sx.x*sx.x + sx.y*sx.y + sx.z*sx.z + sx.w*sx.w + xe*xe;
  float t1 = dx.x + dx.y + dx.z + dx.w;
  float t2 = dx.x*dx.x + dx.y*dx.y + dx.z*dx.z + dx.w*dx.w;
  #pragma unroll
  for(int i=1;i<32;i<<=1){
    s1 += __shfl_xor(s1,i); s2 += __shfl_xor(s2,i);
    t1 += __shfl_xor(t1,i); t2 += __shfl_xor(t2,i);
  }
  float smu = s1*(1.f/160.f);
  float ssc = rsqrtf(s2*(1.f/160.f) - smu*smu + 1e-5f);
  float dmu = t1*(1.f/128.f);
  float dsc = rsqrtf(t2*(1.f/128.f) - dmu*dmu + 1e-5f);
  float4 gs = *(const float4*)(g_s + 4*l), bs = *(const float4*)(b_s + 4*l);
  float4 gd = *(const float4*)(g_d + 4*l), bd = *(const float4*)(b_d + 4*l);
  unsigned r0 = (unsigned)f2bf((sx.x-smu)*ssc*gs.x + bs.x)
              | ((unsigned)f2bf((sx.y-smu)*ssc*gs.y + bs.y) << 16);
  unsigned r1 = (unsigned)f2bf((sx.z-smu)*ssc*gs.z + bs.z)
              | ((unsigned)f2bf((sx.w-smu)*ssc*gs.w + bs.w) << 16);
  uint2 rs; rs.x = r0; rs.y = r1;
  *(uint2*)(dia_s + (size_t)p*160 + 4*l) = rs;
  dia_s[(size_t)p*160 + 128 + l] = f2bf((xe-smu)*ssc*g_s[128+l] + b_s[128+l]);
  unsigned d0 = (unsigned)f2bf((dx.x-dmu)*dsc*gd.x + bd.x)
              | ((unsigned)f2bf((dx.y-dmu)*dsc*gd.y + bd.y) << 16);
  unsigned d1 = (unsigned)f2bf((dx.z-dmu)*dsc*gd.z + bd.z)
              | ((unsigned)f2bf((dx.w-dmu)*dsc*gd.w + bd.w) << 16);
  uint2 rd; rd.x = d0; rd.y = d1;
  *(uint2*)(dia_d + (size_t)p*128 + 4*l) = rd;
}

// ---------------- GEMM core: 64 rows x 128 cols, 8 waves, wave = 64r x 16c
// A in LDS [64][lda] bf16 (staged + synced by caller, read-only here);
// Wf global bf16 fragment-major; wave w owns cols w*16..w*16+15 (nb = w).
// acc[rt][reg] = C[rt*16 + quad*4 + reg][w*16 + m]
template<int NC>
__device__ __forceinline__ void gemm64r8(
  const unsigned short* __restrict__ A, int lda,
  const unsigned short* __restrict__ Wf,
  f32x4* acc, int tid)
{
  int lane = tid & 63, w = tid >> 6, m = lane & 15, quad = lane >> 4;
  const unsigned short* p0 = Wf + (size_t)w*NC*512 + lane*8;
  short8 b0[NC];
  #pragma unroll
  for(int c=0;c<NC;c++) b0[c] = *(const short8*)(p0 + c*512);
  #pragma unroll
  for(int i=0;i<4;i++) acc[i] = (f32x4){0.f,0.f,0.f,0.f};
  #pragma unroll
  for(int c=0;c<NC;c++){
    #pragma unroll
    for(int rt=0; rt<4; rt++){
      short8 af = *(const short8*)(A + (rt*16 + m)*lda + c*32 + quad*8);
      acc[rt] = __builtin_amdgcn_mfma_f32_16x16x32_bf16(af, b0[c], acc[rt], 0,0,0);
    }
  }
}

// ---------------- fused typed q/k/v GEMM + attention scores (8 waves)
__global__ __launch_bounds__(512) void k_qkv(
  const unsigned short* __restrict__ dia_d, const unsigned short* __restrict__ dia_s,
  const unsigned short* __restrict__ Wq_t, const unsigned short* __restrict__ Wk_t,
  const unsigned short* __restrict__ Wv_t,
  const int* __restrict__ cnt_e, const int* __restrict__ off_e,
  float* __restrict__ abuf, unsigned short* __restrict__ vbuf)
{
  __shared__ unsigned short Ad[64*136];
  __shared__ unsigned short As[64*168];
  int bid = blockIdx.x;
  int r = -1, tl0 = 0, accT = 0;
  #pragma unroll
  for(int i=0;i<8;i++){
    int n = cnt_e[i], tt = (n + 63) >> 6;
    if(r < 0 && bid < accT + tt){ r = i; tl0 = bid - accT; }
    accT += tt;
  }
  if(r < 0) return;
  int row0 = off_e[r] + tl0*64;
  int nv = min(64, cnt_e[r] - tl0*64);
  int tid = threadIdx.x;
  {
    int4 z = make_int4(0,0,0,0);
    #pragma unroll
    for(int it=0; it<2; it++){            // stage dia_d tile (1024 int4)
      int idx = it*512 + tid, row = idx >> 4, c = idx & 15;
      int4 v = z;
      if(row < nv) v = *(const int4*)(dia_d + (size_t)(row0+row)*128 + c*8);
      *(int4*)(Ad + row*136 + c*8) = v;
    }
    #pragma unroll
    for(int it=0; it<3; it++){            // stage dia_s tile (1280 int4)
      int idx = it*512 + tid;
      if(idx < 1280){
        int row = idx/20, c = idx%20;
        int4 v = z;
        if(row < nv) v = *(const int4*)(dia_s + (size_t)(row0+row)*160 + c*8);
        *(int4*)(As + row*168 + c*8) = v;
      }
    }
  }
  __syncthreads();                         // A tiles ready; no more barriers
  int lane = tid & 63, w = tid >> 6, m = lane & 15, quad = lane >> 4;
  f32x4 q[4], kk[4], vv[4];
  gemm64r8<4>(Ad, 136, Wq_t + r*16384, q,  tid);
  gemm64r8<5>(As, 168, Wk_t + r*20480, kk, tid);
  // a[row][head] : wave w = head w (cols w*16..w*16+15); reduce over m lanes
  const float inv = 0.08838834764831845f;
  #pragma unroll
  for(int rt=0; rt<4; rt++){
    #pragma unroll
    for(int reg=0; reg<4; reg++){
      float s = q[rt][reg] * kk[rt][reg];
      s += __shfl_xor(s,1); s += __shfl_xor(s,2); s += __shfl_xor(s,4); s += __shfl_xor(s,8);
      int row = rt*16 + quad*4 + reg;
      if(m == 0 && row < nv) abuf[(size_t)(row0+row)*8 + w] = s * inv;
    }
  }
  gemm64r8<5>(As, 168, Wv_t + r*20480, vv, tid);
  #pragma unroll
  for(int rt=0; rt<4; rt++)
  #pragma unroll
  for(int reg=0; reg<4; reg++){
    int row = rt*16 + quad*4 + reg;
    if(row < nv)
      vbuf[(size_t)(row0+row)*128 + w*16 + m] = f2bf(vv[rt][reg]);
  }
}

// ---------------- per-dst softmax + weighted aggregate (no global atomics)
__global__ __launch_bounds__(128) void k_aggr(
  const float* __restrict__ abuf, const unsigned short* __restrict__ vbuf,
  const int* __restrict__ dstlist, const int* __restrict__ off_d,
  const int* __restrict__ npos, const int* __restrict__ ntype,
  const float* __restrict__ h_bias, unsigned short* __restrict__ hpre)
{
  int d = blockIdx.x, tid = threadIdx.x;
  int o0 = off_d[d], cnt = off_d[d+1] - o0;
  __shared__ float den[8];
  if(tid < 8) den[tid] = 0.f;
  __syncthreads();
  for(int idx = tid; idx < cnt*8; idx += 128){
    int i = idx >> 3, h = idx & 7;
    float ex = __expf(abuf[(size_t)dstlist[o0+i]*8 + h]);
    atomicAdd(&den[h], ex);
  }
  __syncthreads();
  int h = tid >> 4;
  float dh = den[h];
  float rd = (dh > 0.f) ? (1.f/dh) : 0.f;
  float acc = 0.f;
  for(int i=0; i<cnt; i++){
    int p = dstlist[o0+i];
    float al = __expf(abuf[(size_t)p*8 + h]) * rd;
    acc += al * bf2f(vbuf[(size_t)p*128 + tid]);
  }
  int t = ntype[d];
  acc += h_bias[t*128 + tid];
  hpre[(size_t)npos[d]*128 + tid] = f2bf(acc);   // write at ntype-sorted row
}

// ---------------- final typed GEMM (Wa) + gate + residual (8 waves)
__global__ __launch_bounds__(512) void k_final(
  const unsigned short* __restrict__ hpre, const unsigned short* __restrict__ Wa_t,
  const int* __restrict__ cnt_n, const int* __restrict__ off_n, const int* __restrict__ nperm,
  const float* __restrict__ skip, const float* __restrict__ src_h, float* __restrict__ out)
{
  __shared__ unsigned short Ah[64*136];
  int bid = blockIdx.x;
  int r = -1, tl0 = 0, accT = 0;
  #pragma unroll
  for(int i=0;i<4;i++){
    int n = cnt_n[i], tt = (n + 63) >> 6;
    if(r < 0 && bid < accT + tt){ r = i; tl0 = bid - accT; }
    accT += tt;
  }
  if(r < 0) return;
  int row0 = off_n[r] + tl0*64;
  int nv = min(64, cnt_n[r] - tl0*64);
  float gate = 1.f / (1.f + __expf(-skip[r]));
  int tid = threadIdx.x;
  int4 z = make_int4(0,0,0,0);
  #pragma unroll
  for(int it=0; it<2; it++){
    int idx = it*512 + tid, row = idx >> 4, c = idx & 15;
    int4 v = z;
    if(row < nv) v = *(const int4*)(hpre + (size_t)(row0+row)*128 + c*8);
    *(int4*)(Ah + row*136 + c*8) = v;
  }
  __syncthreads();
  f32x4 acc[4];
  gemm64r8<4>(Ah, 136, Wa_t + r*16384, acc, tid);
  int lane = tid & 63, w = tid >> 6, m = lane & 15, quad = lane >> 4;
  #pragma unroll
  for(int rt=0; rt<4; rt++)
  #pragma unroll
  for(int reg=0; reg<4; reg++){
    int row = rt*16 + quad*4 + reg;
    if(row < nv){
      int dd = nperm[row0+row];
      int col = w*16 + m;
      out[(size_t)dd*128 + col] = acc[rt][reg]*gate + src_h[(size_t)dd*128 + col]*(1.f - gate);
    }
  }
}

// ---------------------------------------------------------------------------
extern "C" void kernel_launch(void* const* d_in, const int* in_sizes, int n_in,
                              void* d_out, int out_size, void* d_ws, size_t ws_size,
                              hipStream_t stream)
{
  const float* src_h  = (const float*)d_in[0];
  const float* src_tw = (const float*)d_in[1];
  const float* src_tb = (const float*)d_in[2];
  const float* edge_h = (const float*)d_in[3];
  const float* date   = (const float*)d_in[4];
  const int*   src_idx= (const int*)d_in[5];
  const int*   dst_idx= (const int*)d_in[6];
  const int*   etype  = (const int*)d_in[7];
  const int*   ntype  = (const int*)d_in[8];
  const float* Wq     = (const float*)d_in[9];
  const float* Wk     = (const float*)d_in[10];
  const float* Wv     = (const float*)d_in[11];
  const float* Wa     = (const float*)d_in[12];
  const float* h_bias = (const float*)d_in[13];
  const float* skip   = (const float*)d_in[14];
  const float* g_s    = (const float*)d_in[15];
  const float* b_s    = (const float*)d_in[16];
  const float* g_d    = (const float*)d_in[17];
  const float* b_d    = (const float*)d_in[18];
  float* out = (float*)d_out;

  const int E = in_sizes[4];   // date
  const int M = in_sizes[8];   // ntype

  char* base = (char*)d_ws;
  size_t off = 0;
  auto alloc = [&](size_t bytes)->char*{
    off = (off + 255) & ~(size_t)255;
    char* p = base + off; off += bytes; return p;
  };
  // contiguous zero region: cnt_e[8] cur_e[8] cnt_n[4] cur_n[4] cnt_d[M] cur_d[M]
  int* cnt_e = (int*)alloc((size_t)(24 + 2*M)*4);
  int* cur_e = cnt_e + 8;
  int* cnt_n = cur_e + 8;
  int* cur_n = cnt_n + 4;
  int* cnt_d = cur_n + 4;
  int* cur_d = cnt_d + M;
  const int nzero = 24 + 2*M;
  int* off_e = (int*)alloc(9*4);
  int* off_n = (int*)alloc(5*4);
  int* off_d = (int*)alloc((size_t)(M+1)*4);
  int* eperm   = (int*)alloc((size_t)E*4);
  int* dstlist = (int*)alloc((size_t)E*4);
  int* nperm   = (int*)alloc((size_t)M*4);
  int* npos    = (int*)alloc((size_t)M*4);
  unsigned short* Wq_t = (unsigned short*)alloc((size_t)8*128*128*2);
  unsigned short* Wk_t = (unsigned short*)alloc((size_t)8*160*128*2);
  unsigned short* Wv_t = (unsigned short*)alloc((size_t)8*160*128*2);
  unsigned short* Wa_t = (unsigned short*)alloc((size_t)4*128*128*2);
  unsigned short* dia_d = (unsigned short*)alloc((size_t)E*128*2);
  unsigned short* dia_s = (unsigned short*)alloc((size_t)E*160*2);
  unsigned short* vbuf  = (unsigned short*)alloc((size_t)E*128*2);
  unsigned short* hpre  = (unsigned short*)alloc((size_t)M*128*2);
  float* abuf = (float*)alloc((size_t)E*8*4);

  k_zero<<<dim3((nzero+255)/256), dim3(256), 0, stream>>>(cnt_e, nzero);
  k_hist<<<dim3((E+255)/256), dim3(256), 0, stream>>>(etype, dst_idx, ntype, cnt_e, cnt_d, cnt_n, E, M);
  k_scan<<<dim3(1), dim3(1024), 0, stream>>>(cnt_e, off_e, cnt_n, off_n, cnt_d, off_d, M);
  k_scatter<<<dim3((E+255)/256), dim3(256), 0, stream>>>(etype, dst_idx, ntype,
      off_e, cur_e, off_d, cur_d, off_n, cur_n, eperm, dstlist, nperm, npos, E, M);
  k_convw<<<dim3(2048), dim3(256), 0, stream>>>(Wq, Wk, Wv, Wa, Wq_t, Wk_t, Wv_t, Wa_t);
  k_prep<<<dim3((E+7)/8), dim3(256), 0, stream>>>(src_h, src_tw, src_tb, edge_h, date,
      src_idx, dst_idx, eperm, g_s, b_s, g_d, b_d, dia_s, dia_d, E);
  k_qkv<<<dim3(E/64 + 9), dim3(512), 0, stream>>>(dia_d, dia_s, Wq_t, Wk_t, Wv_t,
      cnt_e, off_e, abuf, vbuf);
  k_aggr<<<dim3(M), dim3(128), 0, stream>>>(abuf, vbuf, dstlist, off_d, npos, ntype, h_bias, hpre);
  k_final<<<dim3(M/64 + 5), dim3(512), 0, stream>>>(hpre, Wa_t, cnt_n, off_n, nperm, skip, src_h, out);
}

// Round 5
// 259.972 us; speedup vs baseline: 1.1967x; 1.0178x over previous
//
#include <hip/hip_runtime.h>

// ---------------------------------------------------------------------------
// HTGT layer: sort-by-type + bf16 MFMA pipeline
// dims (fixed by problem): N=50000 M=10000 E=100000, in=128 e=32 out=128 td=32
// R=8 etypes, T=4 ntypes, H=8 heads, hs=16
// R2: k_hist/k_scatter hot-counter atomics hierarchized
// R3: register-resident-B GEMMs (fragment-major weights)
// R4 (REVERTED): prep-into-qkv fusion -> occupancy collapse
// R5: k_prep 2 edges/wave, single-pass LN, float4 gathers
// R6: 8-wave k_qkv (no speedup; LDS reads doubled, conflicts doubled)
// R7: k_qkv goes LDS-FREE. k_prep writes dia_s/dia_d in MFMA fragment-major
//     layout (16-edge blocks, 1KB-coalesced per (chunk,quad)); k_qkv loads
//     A-fragments directly from global (L2/L3-hot). No staging, no barrier,
//     no LDS -> no bank conflicts, no LDS residency cap, all loads are
//     independent coalesced 1KB blocks. etype regions padded to 64 rows
//     (off_e padded cumsum; eperm zero-filled -> pad rows = edge 0, finite,
//     outputs masked by nv). Wave = 32 rows x 32 cols (2 rowgrp x 4 colgrp).
// ---------------------------------------------------------------------------

typedef __attribute__((ext_vector_type(8))) short short8;
typedef __attribute__((ext_vector_type(4))) float f32x4;

__device__ __forceinline__ unsigned short f2bf(float f){
  union { float f; unsigned u; } x; x.f = f;
  unsigned r = x.u + 0x7FFFu + ((x.u >> 16) & 1u);
  return (unsigned short)(r >> 16);
}
__device__ __forceinline__ float bf2f(unsigned short b){
  union { unsigned u; float f; } x; x.u = ((unsigned)b) << 16;
  return x.f;
}

// ---------------- setup kernels ----------------

__global__ void k_zero(int* __restrict__ p, int n){
  int i = blockIdx.x*256 + threadIdx.x;
  if(i < n) p[i] = 0;
}

__global__ __launch_bounds__(256) void k_hist(
    const int* __restrict__ etype, const int* __restrict__ dst_idx,
    const int* __restrict__ ntype,
    int* cnt_e, int* cnt_d, int* cnt_n, int E, int M){
  __shared__ int le[8], ln[4];
  int tid = threadIdx.x;
  if(tid < 8) le[tid] = 0;
  if(tid < 4) ln[tid] = 0;
  __syncthreads();
  int g = blockIdx.x*256 + tid;
  if(g < E){ atomicAdd(&le[etype[g]], 1); atomicAdd(&cnt_d[dst_idx[g]], 1); }
  if(g < M){ atomicAdd(&ln[ntype[g]], 1); }
  __syncthreads();
  if(tid < 8 && le[tid]) atomicAdd(&cnt_e[tid], le[tid]);
  if(tid < 4 && ln[tid]) atomicAdd(&cnt_n[tid], ln[tid]);
}

// off_e is a PADDED cumsum: each etype region starts at a multiple of 64.
__global__ __launch_bounds__(1024) void k_scan(const int* __restrict__ cnt_e, int* off_e,
                                               const int* __restrict__ cnt_n, int* off_n,
                                               const int* __restrict__ cnt_d, int* off_d, int M){
  __shared__ int part[1024];
  int tid = threadIdx.x;
  if(tid == 0){
    int s = 0;
    for(int i=0;i<8;i++){ off_e[i]=s; s += ((cnt_e[i]+63)>>6)<<6; } off_e[8]=s;
    s = 0;
    for(int i=0;i<4;i++){ off_n[i]=s; s+=cnt_n[i]; } off_n[4]=s;
  }
  int per = (M + 1023) >> 10;
  int s = 0;
  for(int j=0;j<per;j++){ int idx = tid*per + j; if(idx < M) s += cnt_d[idx]; }
  part[tid] = s; __syncthreads();
  for(int o=1;o<1024;o<<=1){
    int v = (tid >= o) ? part[tid-o] : 0;
    __syncthreads();
    part[tid] += v;
    __syncthreads();
  }
  int run = (tid == 0) ? 0 : part[tid-1];
  for(int j=0;j<per;j++){
    int idx = tid*per + j;
    if(idx < M){ off_d[idx] = run; run += cnt_d[idx]; }
  }
  if(tid == 1023) off_d[M] = run;
}

__global__ __launch_bounds__(256) void k_scatter(
    const int* __restrict__ etype, const int* __restrict__ dst_idx,
    const int* __restrict__ ntype,
    const int* __restrict__ off_e, int* cur_e,
    const int* __restrict__ off_d, int* cur_d,
    const int* __restrict__ off_n, int* cur_n,
    int* eperm, int* dstlist, int* nperm, int* npos, int E, int M){
  __shared__ int lcnt[8], lbase[8], lnc[4], lnb[4];
  int tid = threadIdx.x;
  if(tid < 8) lcnt[tid] = 0;
  if(tid < 4) lnc[tid] = 0;
  __syncthreads();
  int g = blockIdx.x*256 + tid;
  int r = 0, lrank = 0, t = 0, nrank = 0;
  bool inE = (g < E), inM = (g < M);
  if(inE){ r = etype[g]; lrank = atomicAdd(&lcnt[r], 1); }
  if(inM){ t = ntype[g]; nrank = atomicAdd(&lnc[t], 1); }
  __syncthreads();
  if(tid < 8 && lcnt[tid]) lbase[tid] = atomicAdd(&cur_e[tid], lcnt[tid]);
  if(tid < 4 && lnc[tid])  lnb[tid]   = atomicAdd(&cur_n[tid], lnc[tid]);
  __syncthreads();
  if(inE){
    int p = off_e[r] + lbase[r] + lrank;
    eperm[p] = g;
    int d = dst_idx[g];
    int q = off_d[d] + atomicAdd(&cur_d[d], 1);   // ~10-way contention, benign
    dstlist[q] = p;                               // etype-sorted (padded) position
  }
  if(inM){
    int np = off_n[t] + lnb[t] + nrank;
    npos[g] = np;
    nperm[np] = g;
  }
}

// convert weights to bf16 FRAGMENT-MAJOR layout:
//   [r][nb][c][quad][m][j]  (n = nb*16+m = out col, k = c*32+quad*8+j = in dim)
// lane l (= quad*16+m) reads 16B at block_base + l*16.
__global__ void k_convw(const float* __restrict__ Wq, const float* __restrict__ Wk,
                        const float* __restrict__ Wv, const float* __restrict__ Wa,
                        unsigned short* Wq_t, unsigned short* Wk_t,
                        unsigned short* Wv_t, unsigned short* Wa_t){
  int tid = blockIdx.x*256 + threadIdx.x;
  if(tid < 131072){                                  // Wq: 8 x 128(k) x 128(n)
    int r = tid >> 14, rem = tid & 16383, k = rem >> 7, n = rem & 127;
    int nb=n>>4, m=n&15, c=k>>5, quad=(k>>3)&3, j=k&7;
    Wq_t[r*16384 + ((nb*4 + c)*4 + quad)*128 + m*8 + j] = f2bf(Wq[tid]);
  } else if(tid < 294912){                           // Wk: 8 x 160(k) x 128(n)
    int u = tid - 131072;
    int r = u / 20480, rem = u - r*20480, k = rem >> 7, n = rem & 127;
    int nb=n>>4, m=n&15, c=k>>5, quad=(k>>3)&3, j=k&7;
    Wk_t[r*20480 + ((nb*5 + c)*4 + quad)*128 + m*8 + j] = f2bf(Wk[u]);
  } else if(tid < 458752){                           // Wv: 8 x 160(k) x 128(n)
    int u = tid - 294912;
    int r = u / 20480, rem = u - r*20480, k = rem >> 7, n = rem & 127;
    int nb=n>>4, m=n&15, c=k>>5, quad=(k>>3)&3, j=k&7;
    Wv_t[r*20480 + ((nb*5 + c)*4 + quad)*128 + m*8 + j] = f2bf(Wv[u]);
  } else if(tid < 524288){                           // Wa: 4 x 128(k) x 128(n)
    int u = tid - 458752;
    int r = u >> 14, rem = u & 16383, k = rem >> 7, n = rem & 127;
    int nb=n>>4, m=n&15, c=k>>5, quad=(k>>3)&3, j=k&7;
    Wa_t[r*16384 + ((nb*4 + c)*4 + quad)*128 + m*8 + j] = f2bf(Wa[u]);
  }
}

// ---------------- prep: gather + temporal encode + LN, written FRAGMENT-MAJOR
// dia_d: per 16-edge block, 4 chunks x [quad][m][j]  (2048 shorts = 4KB)
// dia_s: per 16-edge block, 5 chunks                 (2560 shorts = 5KB)
// edge p (padded pos), lane l (0..31): elems k=4l..4l+3  (+ edge elem 128+l)
// addr within block: (c*4+quad)*128 + m*8 + j,  c*4+quad = k>>3, m = p&15.
__global__ __launch_bounds__(256) void k_prep(
  const float* __restrict__ src_h, const float* __restrict__ src_tw, const float* __restrict__ src_tb,
  const float* __restrict__ edge_h, const float* __restrict__ date,
  const int* __restrict__ src_idx, const int* __restrict__ dst_idx, const int* __restrict__ eperm,
  const float* __restrict__ g_s, const float* __restrict__ b_s,
  const float* __restrict__ g_d, const float* __restrict__ b_d,
  unsigned short* __restrict__ dia_s, unsigned short* __restrict__ dia_d, int Ep)
{
  int p = blockIdx.x*8 + (threadIdx.x >> 5);
  if(p >= Ep) return;
  int l = threadIdx.x & 31;
  int e = eperm[p];                          // pad rows: e = 0 (finite data)
  float t = date[e];
  int s = src_idx[e], d = dst_idx[e];
  float4 hs = *(const float4*)(src_h + (size_t)s*128 + 4*l);
  float4 hd = *(const float4*)(src_h + (size_t)d*128 + 4*l);
  float xe = edge_h[(size_t)e*32 + l];
  float4 sx = hs, dx = hd;
  if(l < 8){                                 // elems 0..31 get temporal encode
    float4 w4, c4;
    w4 = *(const float4*)(src_tw + (size_t)s*32 + 4*l);
    c4 = *(const float4*)(src_tb + (size_t)s*32 + 4*l);
    sx.x = __sinf(w4.x*t + c4.x) * hs.x;
    sx.y = __sinf(w4.y*t + c4.y) * hs.y;
    sx.z = __sinf(w4.z*t + c4.z) * hs.z;
    sx.w = __sinf(w4.w*t + c4.w) * hs.w;
    w4 = *(const float4*)(src_tw + (size_t)d*32 + 4*l);
    c4 = *(const float4*)(src_tb + (size_t)d*32 + 4*l);
    dx.x = __sinf(w4.x*t + c4.x) * hd.x;
    dx.y = __sinf(w4.y*t + c4.y) * hd.y;
    dx.z = __sinf(w4.z*t + c4.z) * hd.z;
    dx.w = __sinf(w4.w*t + c4.w) * hd.w;
  }
  float s1 = sx.x + sx.y + sx.z + sx.w + xe;
  float s2 = sx.x*sx.x + sx.y*sx.y + sx.z*sx.z + sx.w*sx.w + xe*xe;
  float t1 = dx.x + dx.y + dx.z + dx.w;
  float t2 = dx.x*dx.x + dx.y*dx.y + dx.z*dx.z + dx.w*dx.w;
  #pragma unroll
  for(int i=1;i<32;i<<=1){
    s1 += __shfl_xor(s1,i); s2 += __shfl_xor(s2,i);
    t1 += __shfl_xor(t1,i); t2 += __shfl_xor(t2,i);
  }
  float smu = s1*(1.f/160.f);
  float ssc = rsqrtf(s2*(1.f/160.f) - smu*smu + 1e-5f);
  float dmu = t1*(1.f/128.f);
  float dsc = rsqrtf(t2*(1.f/128.f) - dmu*dmu + 1e-5f);
  float4 gs = *(const float4*)(g_s + 4*l), bs = *(const float4*)(b_s + 4*l);
  float4 gd = *(const float4*)(g_d + 4*l), bd = *(const float4*)(b_d + 4*l);
  unsigned r0 = (unsigned)f2bf((sx.x-smu)*ssc*gs.x + bs.x)
              | ((unsigned)f2bf((sx.y-smu)*ssc*gs.y + bs.y) << 16);
  unsigned r1 = (unsigned)f2bf((sx.z-smu)*ssc*gs.z + bs.z)
              | ((unsigned)f2bf((sx.w-smu)*ssc*gs.w + bs.w) << 16);
  unsigned d0 = (unsigned)f2bf((dx.x-dmu)*dsc*gd.x + bd.x)
              | ((unsigned)f2bf((dx.y-dmu)*dsc*gd.y + bd.y) << 16);
  unsigned d1 = (unsigned)f2bf((dx.z-dmu)*dsc*gd.z + bd.z)
              | ((unsigned)f2bf((dx.w-dmu)*dsc*gd.w + bd.w) << 16);
  int m = p & 15;
  int cq = l >> 1;                 // (4l)>>3 = c*4+quad
  int j  = (4*l) & 7;              // 0 or 4
  size_t bs_off = (size_t)(p>>4)*2560;
  size_t bd_off = (size_t)(p>>4)*2048;
  uint2 rs; rs.x = r0; rs.y = r1;
  uint2 rd; rd.x = d0; rd.y = d1;
  *(uint2*)(dia_s + bs_off + cq*128 + m*8 + j) = rs;
  *(uint2*)(dia_d + bd_off + cq*128 + m*8 + j) = rd;
  // edge elem k = 128+l -> chunk 4, quad = l>>3, j = l&7
  dia_s[bs_off + (16 + (l>>3))*128 + m*8 + (l&7)] = f2bf((xe-smu)*ssc*g_s[128+l] + b_s[128+l]);
}

// ---------------- LDS-free GEMM: wave covers 32 rows x 32 cols
// A fragment-major in global (dia), B fragment-major in global (Wf).
// acc[rt*2+ct] -> C[rowgrp*32+rt*16+quad*4+reg][colgrp*32+ct*16+m]
template<int NC>
__device__ __forceinline__ void gemm_nolds(
  const unsigned short* __restrict__ dia, int fb0,
  const unsigned short* __restrict__ Wf,
  int rowgrp, int colgrp, int lane, f32x4* acc)
{
  const unsigned short* a0 = dia + (size_t)(fb0 + rowgrp*2    )*NC*512 + lane*8;
  const unsigned short* a1 = dia + (size_t)(fb0 + rowgrp*2 + 1)*NC*512 + lane*8;
  const unsigned short* b0 = Wf + (size_t)(2*colgrp)*NC*512 + lane*8;
  #pragma unroll
  for(int i=0;i<4;i++) acc[i] = (f32x4){0.f,0.f,0.f,0.f};
  #pragma unroll
  for(int c=0;c<NC;c++){
    short8 bf0 = *(const short8*)(b0 + c*512);
    short8 bf1 = *(const short8*)(b0 + NC*512 + c*512);
    short8 af0 = *(const short8*)(a0 + c*512);
    short8 af1 = *(const short8*)(a1 + c*512);
    acc[0] = __builtin_amdgcn_mfma_f32_16x16x32_bf16(af0, bf0, acc[0], 0,0,0);
    acc[1] = __builtin_amdgcn_mfma_f32_16x16x32_bf16(af0, bf1, acc[1], 0,0,0);
    acc[2] = __builtin_amdgcn_mfma_f32_16x16x32_bf16(af1, bf0, acc[2], 0,0,0);
    acc[3] = __builtin_amdgcn_mfma_f32_16x16x32_bf16(af1, bf1, acc[3], 0,0,0);
  }
}

// ---------------- fused typed q/k/v GEMM + attention scores (LDS-free)
__global__ __launch_bounds__(512) void k_qkv(
  const unsigned short* __restrict__ dia_d, const unsigned short* __restrict__ dia_s,
  const unsigned short* __restrict__ Wq_t, const unsigned short* __restrict__ Wk_t,
  const unsigned short* __restrict__ Wv_t,
  const int* __restrict__ cnt_e, const int* __restrict__ off_e,
  float* __restrict__ abuf, unsigned short* __restrict__ vbuf)
{
  int bid = blockIdx.x;
  int r = -1, tl0 = 0, accT = 0;
  #pragma unroll
  for(int i=0;i<8;i++){
    int n = cnt_e[i], tt = (n + 63) >> 6;
    if(r < 0 && bid < accT + tt){ r = i; tl0 = bid - accT; }
    accT += tt;
  }
  if(r < 0) return;
  int row0 = off_e[r] + tl0*64;              // multiple of 64 (padded off_e)
  int nv = min(64, cnt_e[r] - tl0*64);
  int tid = threadIdx.x;
  int lane = tid & 63, w = tid >> 6, m = lane & 15, quad = lane >> 4;
  int rowgrp = w & 1, colgrp = w >> 1;
  int fb0 = row0 >> 4;
  f32x4 q[4], kk[4], vv[4];
  gemm_nolds<4>(dia_d, fb0, Wq_t + r*16384, rowgrp, colgrp, lane, q);
  gemm_nolds<5>(dia_s, fb0, Wk_t + r*20480, rowgrp, colgrp, lane, kk);
  const float inv = 0.08838834764831845f;
  #pragma unroll
  for(int rt=0; rt<2; rt++)
  #pragma unroll
  for(int ct=0; ct<2; ct++){
    #pragma unroll
    for(int reg=0; reg<4; reg++){
      float s = q[rt*2+ct][reg] * kk[rt*2+ct][reg];
      s += __shfl_xor(s,1); s += __shfl_xor(s,2); s += __shfl_xor(s,4); s += __shfl_xor(s,8);
      int row = rowgrp*32 + rt*16 + quad*4 + reg;
      if(m == 0 && row < nv) abuf[(size_t)(row0+row)*8 + colgrp*2 + ct] = s * inv;
    }
  }
  gemm_nolds<5>(dia_s, fb0, Wv_t + r*20480, rowgrp, colgrp, lane, vv);
  #pragma unroll
  for(int rt=0; rt<2; rt++)
  #pragma unroll
  for(int ct=0; ct<2; ct++)
  #pragma unroll
  for(int reg=0; reg<4; reg++){
    int row = rowgrp*32 + rt*16 + quad*4 + reg;
    if(row < nv)
      vbuf[(size_t)(row0+row)*128 + colgrp*32 + ct*16 + m] = f2bf(vv[rt*2+ct][reg]);
  }
}

// ---------------- per-dst softmax + weighted aggregate (no global atomics)
__global__ __launch_bounds__(128) void k_aggr(
  const float* __restrict__ abuf, const unsigned short* __restrict__ vbuf,
  const int* __restrict__ dstlist, const int* __restrict__ off_d,
  const int* __restrict__ npos, const int* __restrict__ ntype,
  const float* __restrict__ h_bias, unsigned short* __restrict__ hpre)
{
  int d = blockIdx.x, tid = threadIdx.x;
  int o0 = off_d[d], cnt = off_d[d+1] - o0;
  __shared__ float den[8];
  if(tid < 8) den[tid] = 0.f;
  __syncthreads();
  for(int idx = tid; idx < cnt*8; idx += 128){
    int i = idx >> 3, h = idx & 7;
    float ex = __expf(abuf[(size_t)dstlist[o0+i]*8 + h]);
    atomicAdd(&den[h], ex);
  }
  __syncthreads();
  int h = tid >> 4;
  float dh = den[h];
  float rd = (dh > 0.f) ? (1.f/dh) : 0.f;
  float acc = 0.f;
  for(int i=0; i<cnt; i++){
    int p = dstlist[o0+i];
    float al = __expf(abuf[(size_t)p*8 + h]) * rd;
    acc += al * bf2f(vbuf[(size_t)p*128 + tid]);
  }
  int t = ntype[d];
  acc += h_bias[t*128 + tid];
  hpre[(size_t)npos[d]*128 + tid] = f2bf(acc);   // write at ntype-sorted row
}

// ---------------- GEMM core w/ LDS A (kept for k_final): 8 waves, 16c each
template<int NC>
__device__ __forceinline__ void gemm64r8(
  const unsigned short* __restrict__ A, int lda,
  const unsigned short* __restrict__ Wf,
  f32x4* acc, int tid)
{
  int lane = tid & 63, w = tid >> 6, m = lane & 15, quad = lane >> 4;
  const unsigned short* p0 = Wf + (size_t)w*NC*512 + lane*8;
  short8 b0[NC];
  #pragma unroll
  for(int c=0;c<NC;c++) b0[c] = *(const short8*)(p0 + c*512);
  #pragma unroll
  for(int i=0;i<4;i++) acc[i] = (f32x4){0.f,0.f,0.f,0.f};
  #pragma unroll
  for(int c=0;c<NC;c++){
    #pragma unroll
    for(int rt=0; rt<4; rt++){
      short8 af = *(const short8*)(A + (rt*16 + m)*lda + c*32 + quad*8);
      acc[rt] = __builtin_amdgcn_mfma_f32_16x16x32_bf16(af, b0[c], acc[rt], 0,0,0);
    }
  }
}

// ---------------- final typed GEMM (Wa) + gate + residual (8 waves)
__global__ __launch_bounds__(512) void k_final(
  const unsigned short* __restrict__ hpre, const unsigned short* __restrict__ Wa_t,
  const int* __restrict__ cnt_n, const int* __restrict__ off_n, const int* __restrict__ nperm,
  const float* __restrict__ skip, const float* __restrict__ src_h, float* __restrict__ out)
{
  __shared__ unsigned short Ah[64*136];
  int bid = blockIdx.x;
  int r = -1, tl0 = 0, accT = 0;
  #pragma unroll
  for(int i=0;i<4;i++){
    int n = cnt_n[i], tt = (n + 63) >> 6;
    if(r < 0 && bid < accT + tt){ r = i; tl0 = bid - accT; }
    accT += tt;
  }
  if(r < 0) return;
  int row0 = off_n[r] + tl0*64;
  int nv = min(64, cnt_n[r] - tl0*64);
  float gate = 1.f / (1.f + __expf(-skip[r]));
  int tid = threadIdx.x;
  int4 z = make_int4(0,0,0,0);
  #pragma unroll
  for(int it=0; it<2; it++){
    int idx = it*512 + tid, row = idx >> 4, c = idx & 15;
    int4 v = z;
    if(row < nv) v = *(const int4*)(hpre + (size_t)(row0+row)*128 + c*8);
    *(int4*)(Ah + row*136 + c*8) = v;
  }
  __syncthreads();
  f32x4 acc[4];
  gemm64r8<4>(Ah, 136, Wa_t + r*16384, acc, tid);
  int lane = tid & 63, w = tid >> 6, m = lane & 15, quad = lane >> 4;
  #pragma unroll
  for(int rt=0; rt<4; rt++)
  #pragma unroll
  for(int reg=0; reg<4; reg++){
    int row = rt*16 + quad*4 + reg;
    if(row < nv){
      int dd = nperm[row0+row];
      int col = w*16 + m;
      out[(size_t)dd*128 + col] = acc[rt][reg]*gate + src_h[(size_t)dd*128 + col]*(1.f - gate);
    }
  }
}

// ---------------------------------------------------------------------------
extern "C" void kernel_launch(void* const* d_in, const int* in_sizes, int n_in,
                              void* d_out, int out_size, void* d_ws, size_t ws_size,
                              hipStream_t stream)
{
  const float* src_h  = (const float*)d_in[0];
  const float* src_tw = (const float*)d_in[1];
  const float* src_tb = (const float*)d_in[2];
  const float* edge_h = (const float*)d_in[3];
  const float* date   = (const float*)d_in[4];
  const int*   src_idx= (const int*)d_in[5];
  const int*   dst_idx= (const int*)d_in[6];
  const int*   etype  = (const int*)d_in[7];
  const int*   ntype  = (const int*)d_in[8];
  const float* Wq     = (const float*)d_in[9];
  const float* Wk     = (const float*)d_in[10];
  const float* Wv     = (const float*)d_in[11];
  const float* Wa     = (const float*)d_in[12];
  const float* h_bias = (const float*)d_in[13];
  const float* skip   = (const float*)d_in[14];
  const float* g_s    = (const float*)d_in[15];
  const float* b_s    = (const float*)d_in[16];
  const float* g_d    = (const float*)d_in[17];
  const float* b_d    = (const float*)d_in[18];
  float* out = (float*)d_out;

  const int E = in_sizes[4];   // date
  const int M = in_sizes[8];   // ntype
  const int Ep = E + 8*63;     // upper bound on padded edge count

  char* base = (char*)d_ws;
  size_t off = 0;
  auto alloc = [&](size_t bytes)->char*{
    off = (off + 255) & ~(size_t)255;
    char* p = base + off; off += bytes; return p;
  };
  // contiguous zero region: cnt_e[8] cur_e[8] cnt_n[4] cur_n[4] cnt_d[M] cur_d[M]
  int* cnt_e = (int*)alloc((size_t)(24 + 2*M)*4);
  int* cur_e = cnt_e + 8;
  int* cnt_n = cur_e + 8;
  int* cur_n = cnt_n + 4;
  int* cnt_d = cur_n + 4;
  int* cur_d = cnt_d + M;
  const int nzero = 24 + 2*M;
  int* off_e = (int*)alloc(9*4);
  int* off_n = (int*)alloc(5*4);
  int* off_d = (int*)alloc((size_t)(M+1)*4);
  int* eperm   = (int*)alloc((size_t)Ep*4);
  int* dstlist = (int*)alloc((size_t)E*4);
  int* nperm   = (int*)alloc((size_t)M*4);
  int* npos    = (int*)alloc((size_t)M*4);
  unsigned short* Wq_t = (unsigned short*)alloc((size_t)8*128*128*2);
  unsigned short* Wk_t = (unsigned short*)alloc((size_t)8*160*128*2);
  unsigned short* Wv_t = (unsigned short*)alloc((size_t)8*160*128*2);
  unsigned short* Wa_t = (unsigned short*)alloc((size_t)4*128*128*2);
  unsigned short* dia_d = (unsigned short*)alloc((size_t)(Ep+16)*128*2);
  unsigned short* dia_s = (unsigned short*)alloc((size_t)(Ep+16)*160*2);
  unsigned short* vbuf  = (unsigned short*)alloc((size_t)Ep*128*2);
  unsigned short* hpre  = (unsigned short*)alloc((size_t)M*128*2);
  float* abuf = (float*)alloc((size_t)Ep*8*4);

  k_zero<<<dim3((nzero+255)/256), dim3(256), 0, stream>>>(cnt_e, nzero);
  k_zero<<<dim3((Ep+255)/256), dim3(256), 0, stream>>>(eperm, Ep);
  k_hist<<<dim3((E+255)/256), dim3(256), 0, stream>>>(etype, dst_idx, ntype, cnt_e, cnt_d, cnt_n, E, M);
  k_scan<<<dim3(1), dim3(1024), 0, stream>>>(cnt_e, off_e, cnt_n, off_n, cnt_d, off_d, M);
  k_scatter<<<dim3((E+255)/256), dim3(256), 0, stream>>>(etype, dst_idx, ntype,
      off_e, cur_e, off_d, cur_d, off_n, cur_n, eperm, dstlist, nperm, npos, E, M);
  k_convw<<<dim3(2048), dim3(256), 0, stream>>>(Wq, Wk, Wv, Wa, Wq_t, Wk_t, Wv_t, Wa_t);
  k_prep<<<dim3((Ep+7)/8), dim3(256), 0, stream>>>(src_h, src_tw, src_tb, edge_h, date,
      src_idx, dst_idx, eperm, g_s, b_s, g_d, b_d, dia_s, dia_d, Ep);
  k_qkv<<<dim3(E/64 + 9), dim3(512), 0, stream>>>(dia_d, dia_s, Wq_t, Wk_t, Wv_t,
      cnt_e, off_e, abuf, vbuf);
  k_aggr<<<dim3(M), dim3(128), 0, stream>>>(abuf, vbuf, dstlist, off_d, npos, ntype, h_bias, hpre);
  k_final<<<dim3(M/64 + 5), dim3(512), 0, stream>>>(hpre, Wa_t, cnt_n, off_n, nperm, skip, src_h, out);
}

// Round 6
// 250.571 us; speedup vs baseline: 1.2416x; 1.0375x over previous
//
#include <hip/hip_runtime.h>

// ---------------------------------------------------------------------------
// HTGT layer: sort-by-type + bf16 MFMA pipeline
// dims (fixed by problem): N=50000 M=10000 E=100000, in=128 e=32 out=128 td=32
// R=8 etypes, T=4 ntypes, H=8 heads, hs=16
// R2: k_hist/k_scatter hot-counter atomics hierarchized
// R3: register-resident-B GEMMs (fragment-major weights)
// R4 (REVERTED): prep-into-qkv fusion -> occupancy collapse
// R5: k_prep 2 edges/wave, single-pass LN, float4 gathers
// R6: 8-wave k_qkv (wash)
// R7: LDS-free k_qkv on fragment-major dia (k_qkv 52 -> ~40us)
// R8: k_prep 2 edges per 32-lane group (4/wave): two independent gather
//     chains in flight per group halves the per-edge latency stall
//     (k_prep was 2.2x over its 21.5us BW floor, both pipes <45%).
//     k_aggr: LDS-cache ex[i][h] + dstlist in pass 1 (CAP=64, fallback
//     recompute) -> kills 16x-redundant expf + abuf re-read in pass 2.
// ---------------------------------------------------------------------------

typedef __attribute__((ext_vector_type(8))) short short8;
typedef __attribute__((ext_vector_type(4))) float f32x4;

__device__ __forceinline__ unsigned short f2bf(float f){
  union { float f; unsigned u; } x; x.f = f;
  unsigned r = x.u + 0x7FFFu + ((x.u >> 16) & 1u);
  return (unsigned short)(r >> 16);
}
__device__ __forceinline__ float bf2f(unsigned short b){
  union { unsigned u; float f; } x; x.u = ((unsigned)b) << 16;
  return x.f;
}

// ---------------- setup kernels ----------------

__global__ void k_zero(int* __restrict__ p, int n){
  int i = blockIdx.x*256 + threadIdx.x;
  if(i < n) p[i] = 0;
}

__global__ __launch_bounds__(256) void k_hist(
    const int* __restrict__ etype, const int* __restrict__ dst_idx,
    const int* __restrict__ ntype,
    int* cnt_e, int* cnt_d, int* cnt_n, int E, int M){
  __shared__ int le[8], ln[4];
  int tid = threadIdx.x;
  if(tid < 8) le[tid] = 0;
  if(tid < 4) ln[tid] = 0;
  __syncthreads();
  int g = blockIdx.x*256 + tid;
  if(g < E){ atomicAdd(&le[etype[g]], 1); atomicAdd(&cnt_d[dst_idx[g]], 1); }
  if(g < M){ atomicAdd(&ln[ntype[g]], 1); }
  __syncthreads();
  if(tid < 8 && le[tid]) atomicAdd(&cnt_e[tid], le[tid]);
  if(tid < 4 && ln[tid]) atomicAdd(&cnt_n[tid], ln[tid]);
}

// off_e is a PADDED cumsum: each etype region starts at a multiple of 64.
__global__ __launch_bounds__(1024) void k_scan(const int* __restrict__ cnt_e, int* off_e,
                                               const int* __restrict__ cnt_n, int* off_n,
                                               const int* __restrict__ cnt_d, int* off_d, int M){
  __shared__ int part[1024];
  int tid = threadIdx.x;
  if(tid == 0){
    int s = 0;
    for(int i=0;i<8;i++){ off_e[i]=s; s += ((cnt_e[i]+63)>>6)<<6; } off_e[8]=s;
    s = 0;
    for(int i=0;i<4;i++){ off_n[i]=s; s+=cnt_n[i]; } off_n[4]=s;
  }
  int per = (M + 1023) >> 10;
  int s = 0;
  for(int j=0;j<per;j++){ int idx = tid*per + j; if(idx < M) s += cnt_d[idx]; }
  part[tid] = s; __syncthreads();
  for(int o=1;o<1024;o<<=1){
    int v = (tid >= o) ? part[tid-o] : 0;
    __syncthreads();
    part[tid] += v;
    __syncthreads();
  }
  int run = (tid == 0) ? 0 : part[tid-1];
  for(int j=0;j<per;j++){
    int idx = tid*per + j;
    if(idx < M){ off_d[idx] = run; run += cnt_d[idx]; }
  }
  if(tid == 1023) off_d[M] = run;
}

__global__ __launch_bounds__(256) void k_scatter(
    const int* __restrict__ etype, const int* __restrict__ dst_idx,
    const int* __restrict__ ntype,
    const int* __restrict__ off_e, int* cur_e,
    const int* __restrict__ off_d, int* cur_d,
    const int* __restrict__ off_n, int* cur_n,
    int* eperm, int* dstlist, int* nperm, int* npos, int E, int M){
  __shared__ int lcnt[8], lbase[8], lnc[4], lnb[4];
  int tid = threadIdx.x;
  if(tid < 8) lcnt[tid] = 0;
  if(tid < 4) lnc[tid] = 0;
  __syncthreads();
  int g = blockIdx.x*256 + tid;
  int r = 0, lrank = 0, t = 0, nrank = 0;
  bool inE = (g < E), inM = (g < M);
  if(inE){ r = etype[g]; lrank = atomicAdd(&lcnt[r], 1); }
  if(inM){ t = ntype[g]; nrank = atomicAdd(&lnc[t], 1); }
  __syncthreads();
  if(tid < 8 && lcnt[tid]) lbase[tid] = atomicAdd(&cur_e[tid], lcnt[tid]);
  if(tid < 4 && lnc[tid])  lnb[tid]   = atomicAdd(&cur_n[tid], lnc[tid]);
  __syncthreads();
  if(inE){
    int p = off_e[r] + lbase[r] + lrank;
    eperm[p] = g;
    int d = dst_idx[g];
    int q = off_d[d] + atomicAdd(&cur_d[d], 1);   // ~10-way contention, benign
    dstlist[q] = p;                               // etype-sorted (padded) position
  }
  if(inM){
    int np = off_n[t] + lnb[t] + nrank;
    npos[g] = np;
    nperm[np] = g;
  }
}

// convert weights to bf16 FRAGMENT-MAJOR layout:
//   [r][nb][c][quad][m][j]  (n = nb*16+m = out col, k = c*32+quad*8+j = in dim)
// lane l (= quad*16+m) reads 16B at block_base + l*16.
__global__ void k_convw(const float* __restrict__ Wq, const float* __restrict__ Wk,
                        const float* __restrict__ Wv, const float* __restrict__ Wa,
                        unsigned short* Wq_t, unsigned short* Wk_t,
                        unsigned short* Wv_t, unsigned short* Wa_t){
  int tid = blockIdx.x*256 + threadIdx.x;
  if(tid < 131072){                                  // Wq: 8 x 128(k) x 128(n)
    int r = tid >> 14, rem = tid & 16383, k = rem >> 7, n = rem & 127;
    int nb=n>>4, m=n&15, c=k>>5, quad=(k>>3)&3, j=k&7;
    Wq_t[r*16384 + ((nb*4 + c)*4 + quad)*128 + m*8 + j] = f2bf(Wq[tid]);
  } else if(tid < 294912){                           // Wk: 8 x 160(k) x 128(n)
    int u = tid - 131072;
    int r = u / 20480, rem = u - r*20480, k = rem >> 7, n = rem & 127;
    int nb=n>>4, m=n&15, c=k>>5, quad=(k>>3)&3, j=k&7;
    Wk_t[r*20480 + ((nb*5 + c)*4 + quad)*128 + m*8 + j] = f2bf(Wk[u]);
  } else if(tid < 458752){                           // Wv: 8 x 160(k) x 128(n)
    int u = tid - 294912;
    int r = u / 20480, rem = u - r*20480, k = rem >> 7, n = rem & 127;
    int nb=n>>4, m=n&15, c=k>>5, quad=(k>>3)&3, j=k&7;
    Wv_t[r*20480 + ((nb*5 + c)*4 + quad)*128 + m*8 + j] = f2bf(Wv[u]);
  } else if(tid < 524288){                           // Wa: 4 x 128(k) x 128(n)
    int u = tid - 458752;
    int r = u >> 14, rem = u & 16383, k = rem >> 7, n = rem & 127;
    int nb=n>>4, m=n&15, c=k>>5, quad=(k>>3)&3, j=k&7;
    Wa_t[r*16384 + ((nb*4 + c)*4 + quad)*128 + m*8 + j] = f2bf(Wa[u]);
  }
}

// ---------------- prep: gather + temporal encode + LN, written FRAGMENT-MAJOR
// 2 edges per 32-lane group (4/wave): two independent gather chains in
// flight per group. Lane l covers elems 4l..4l+3 (float4) + edge elem l.
// dia_d: per 16-edge block, 4 chunks x [quad][m][j]; dia_s: 5 chunks.
__global__ __launch_bounds__(256) void k_prep(
  const float* __restrict__ src_h, const float* __restrict__ src_tw, const float* __restrict__ src_tb,
  const float* __restrict__ edge_h, const float* __restrict__ date,
  const int* __restrict__ src_idx, const int* __restrict__ dst_idx, const int* __restrict__ eperm,
  const float* __restrict__ g_s, const float* __restrict__ b_s,
  const float* __restrict__ g_d, const float* __restrict__ b_d,
  unsigned short* __restrict__ dia_s, unsigned short* __restrict__ dia_d, int Ep)
{
  int grp = blockIdx.x*8 + (threadIdx.x >> 5);
  int p0 = grp*2;
  if(p0 >= Ep) return;
  int l = threadIdx.x & 31;
  int pp[2]; pp[0] = p0; pp[1] = min(p0+1, Ep-1);
  int e[2];
  #pragma unroll
  for(int u=0;u<2;u++) e[u] = eperm[pp[u]];
  float t[2]; int s[2], d[2];
  #pragma unroll
  for(int u=0;u<2;u++){ t[u] = date[e[u]]; s[u] = src_idx[e[u]]; d[u] = dst_idx[e[u]]; }
  float4 sx[2], dx[2]; float xe[2];
  #pragma unroll
  for(int u=0;u<2;u++){
    sx[u] = *(const float4*)(src_h + (size_t)s[u]*128 + 4*l);   // hs
    dx[u] = *(const float4*)(src_h + (size_t)d[u]*128 + 4*l);   // hd
    xe[u] = edge_h[(size_t)e[u]*32 + l];
  }
  if(l < 8){                                 // elems 0..31 get temporal encode
    #pragma unroll
    for(int u=0;u<2;u++){
      float4 w4 = *(const float4*)(src_tw + (size_t)s[u]*32 + 4*l);
      float4 c4 = *(const float4*)(src_tb + (size_t)s[u]*32 + 4*l);
      sx[u].x = __sinf(w4.x*t[u] + c4.x) * sx[u].x;
      sx[u].y = __sinf(w4.y*t[u] + c4.y) * sx[u].y;
      sx[u].z = __sinf(w4.z*t[u] + c4.z) * sx[u].z;
      sx[u].w = __sinf(w4.w*t[u] + c4.w) * sx[u].w;
      w4 = *(const float4*)(src_tw + (size_t)d[u]*32 + 4*l);
      c4 = *(const float4*)(src_tb + (size_t)d[u]*32 + 4*l);
      dx[u].x = __sinf(w4.x*t[u] + c4.x) * dx[u].x;
      dx[u].y = __sinf(w4.y*t[u] + c4.y) * dx[u].y;
      dx[u].z = __sinf(w4.z*t[u] + c4.z) * dx[u].z;
      dx[u].w = __sinf(w4.w*t[u] + c4.w) * dx[u].w;
    }
  }
  float a1[2], a2[2], b1[2], b2[2];
  #pragma unroll
  for(int u=0;u<2;u++){
    a1[u] = sx[u].x + sx[u].y + sx[u].z + sx[u].w + xe[u];
    a2[u] = sx[u].x*sx[u].x + sx[u].y*sx[u].y + sx[u].z*sx[u].z + sx[u].w*sx[u].w + xe[u]*xe[u];
    b1[u] = dx[u].x + dx[u].y + dx[u].z + dx[u].w;
    b2[u] = dx[u].x*dx[u].x + dx[u].y*dx[u].y + dx[u].z*dx[u].z + dx[u].w*dx[u].w;
  }
  #pragma unroll
  for(int i=1;i<32;i<<=1){
    #pragma unroll
    for(int u=0;u<2;u++){
      a1[u] += __shfl_xor(a1[u],i); a2[u] += __shfl_xor(a2[u],i);
      b1[u] += __shfl_xor(b1[u],i); b2[u] += __shfl_xor(b2[u],i);
    }
  }
  float4 gs = *(const float4*)(g_s + 4*l), bs = *(const float4*)(b_s + 4*l);
  float4 gd = *(const float4*)(g_d + 4*l), bd = *(const float4*)(b_d + 4*l);
  float gs2 = g_s[128+l], bs2 = b_s[128+l];
  int cq = l >> 1;                 // (4l)>>3
  int j  = (4*l) & 7;              // 0 or 4
  #pragma unroll
  for(int u=0;u<2;u++){
    float smu = a1[u]*(1.f/160.f);
    float ssc = rsqrtf(a2[u]*(1.f/160.f) - smu*smu + 1e-5f);
    float dmu = b1[u]*(1.f/128.f);
    float dsc = rsqrtf(b2[u]*(1.f/128.f) - dmu*dmu + 1e-5f);
    unsigned r0 = (unsigned)f2bf((sx[u].x-smu)*ssc*gs.x + bs.x)
                | ((unsigned)f2bf((sx[u].y-smu)*ssc*gs.y + bs.y) << 16);
    unsigned r1 = (unsigned)f2bf((sx[u].z-smu)*ssc*gs.z + bs.z)
                | ((unsigned)f2bf((sx[u].w-smu)*ssc*gs.w + bs.w) << 16);
    unsigned d0 = (unsigned)f2bf((dx[u].x-dmu)*dsc*gd.x + bd.x)
                | ((unsigned)f2bf((dx[u].y-dmu)*dsc*gd.y + bd.y) << 16);
    unsigned d1 = (unsigned)f2bf((dx[u].z-dmu)*dsc*gd.z + bd.z)
                | ((unsigned)f2bf((dx[u].w-dmu)*dsc*gd.w + bd.w) << 16);
    int p = pp[u];
    int m = p & 15;
    size_t bs_off = (size_t)(p>>4)*2560;
    size_t bd_off = (size_t)(p>>4)*2048;
    uint2 rs; rs.x = r0; rs.y = r1;
    uint2 rd; rd.x = d0; rd.y = d1;
    *(uint2*)(dia_s + bs_off + cq*128 + m*8 + j) = rs;
    *(uint2*)(dia_d + bd_off + cq*128 + m*8 + j) = rd;
    dia_s[bs_off + (16 + (l>>3))*128 + m*8 + (l&7)] = f2bf((xe[u]-smu)*ssc*gs2 + bs2);
  }
}

// ---------------- LDS-free GEMM: wave covers 32 rows x 32 cols
// A fragment-major in global (dia), B fragment-major in global (Wf).
// acc[rt*2+ct] -> C[rowgrp*32+rt*16+quad*4+reg][colgrp*32+ct*16+m]
template<int NC>
__device__ __forceinline__ void gemm_nolds(
  const unsigned short* __restrict__ dia, int fb0,
  const unsigned short* __restrict__ Wf,
  int rowgrp, int colgrp, int lane, f32x4* acc)
{
  const unsigned short* a0 = dia + (size_t)(fb0 + rowgrp*2    )*NC*512 + lane*8;
  const unsigned short* a1 = dia + (size_t)(fb0 + rowgrp*2 + 1)*NC*512 + lane*8;
  const unsigned short* b0 = Wf + (size_t)(2*colgrp)*NC*512 + lane*8;
  #pragma unroll
  for(int i=0;i<4;i++) acc[i] = (f32x4){0.f,0.f,0.f,0.f};
  #pragma unroll
  for(int c=0;c<NC;c++){
    short8 bf0 = *(const short8*)(b0 + c*512);
    short8 bf1 = *(const short8*)(b0 + NC*512 + c*512);
    short8 af0 = *(const short8*)(a0 + c*512);
    short8 af1 = *(const short8*)(a1 + c*512);
    acc[0] = __builtin_amdgcn_mfma_f32_16x16x32_bf16(af0, bf0, acc[0], 0,0,0);
    acc[1] = __builtin_amdgcn_mfma_f32_16x16x32_bf16(af0, bf1, acc[1], 0,0,0);
    acc[2] = __builtin_amdgcn_mfma_f32_16x16x32_bf16(af1, bf0, acc[2], 0,0,0);
    acc[3] = __builtin_amdgcn_mfma_f32_16x16x32_bf16(af1, bf1, acc[3], 0,0,0);
  }
}

// ---------------- fused typed q/k/v GEMM + attention scores (LDS-free)
__global__ __launch_bounds__(512) void k_qkv(
  const unsigned short* __restrict__ dia_d, const unsigned short* __restrict__ dia_s,
  const unsigned short* __restrict__ Wq_t, const unsigned short* __restrict__ Wk_t,
  const unsigned short* __restrict__ Wv_t,
  const int* __restrict__ cnt_e, const int* __restrict__ off_e,
  float* __restrict__ abuf, unsigned short* __restrict__ vbuf)
{
  int bid = blockIdx.x;
  int r = -1, tl0 = 0, accT = 0;
  #pragma unroll
  for(int i=0;i<8;i++){
    int n = cnt_e[i], tt = (n + 63) >> 6;
    if(r < 0 && bid < accT + tt){ r = i; tl0 = bid - accT; }
    accT += tt;
  }
  if(r < 0) return;
  int row0 = off_e[r] + tl0*64;              // multiple of 64 (padded off_e)
  int nv = min(64, cnt_e[r] - tl0*64);
  int tid = threadIdx.x;
  int lane = tid & 63, w = tid >> 6, m = lane & 15, quad = lane >> 4;
  int rowgrp = w & 1, colgrp = w >> 1;
  int fb0 = row0 >> 4;
  f32x4 q[4], kk[4], vv[4];
  gemm_nolds<4>(dia_d, fb0, Wq_t + r*16384, rowgrp, colgrp, lane, q);
  gemm_nolds<5>(dia_s, fb0, Wk_t + r*20480, rowgrp, colgrp, lane, kk);
  const float inv = 0.08838834764831845f;
  #pragma unroll
  for(int rt=0; rt<2; rt++)
  #pragma unroll
  for(int ct=0; ct<2; ct++){
    #pragma unroll
    for(int reg=0; reg<4; reg++){
      float s = q[rt*2+ct][reg] * kk[rt*2+ct][reg];
      s += __shfl_xor(s,1); s += __shfl_xor(s,2); s += __shfl_xor(s,4); s += __shfl_xor(s,8);
      int row = rowgrp*32 + rt*16 + quad*4 + reg;
      if(m == 0 && row < nv) abuf[(size_t)(row0+row)*8 + colgrp*2 + ct] = s * inv;
    }
  }
  gemm_nolds<5>(dia_s, fb0, Wv_t + r*20480, rowgrp, colgrp, lane, vv);
  #pragma unroll
  for(int rt=0; rt<2; rt++)
  #pragma unroll
  for(int ct=0; ct<2; ct++)
  #pragma unroll
  for(int reg=0; reg<4; reg++){
    int row = rowgrp*32 + rt*16 + quad*4 + reg;
    if(row < nv)
      vbuf[(size_t)(row0+row)*128 + colgrp*32 + ct*16 + m] = f2bf(vv[rt*2+ct][reg]);
  }
}

// ---------------- per-dst softmax + weighted aggregate (no global atomics)
// pass 1 caches ex[i][h] + dstlist in LDS (CAP=64 >> max bucket ~30;
// correct fallback recompute for i>=CAP).
__global__ __launch_bounds__(128) void k_aggr(
  const float* __restrict__ abuf, const unsigned short* __restrict__ vbuf,
  const int* __restrict__ dstlist, const int* __restrict__ off_d,
  const int* __restrict__ npos, const int* __restrict__ ntype,
  const float* __restrict__ h_bias, unsigned short* __restrict__ hpre)
{
  const int CAP = 64;
  int d = blockIdx.x, tid = threadIdx.x;
  int o0 = off_d[d], cnt = off_d[d+1] - o0;
  __shared__ float den[8];
  __shared__ float exs[CAP*8];
  __shared__ int dl[CAP];
  if(tid < 8) den[tid] = 0.f;
  __syncthreads();
  float part = 0.f;
  int h8 = tid & 7, i0 = tid >> 3;
  for(int i = i0; i < cnt; i += 16){
    int p = dstlist[o0+i];
    float ex = __expf(abuf[(size_t)p*8 + h8]);
    part += ex;
    if(i < CAP){ exs[i*8 + h8] = ex; if(h8 == 0) dl[i] = p; }
  }
  if(part != 0.f) atomicAdd(&den[h8], part);
  __syncthreads();
  int h = tid >> 4;
  float dh = den[h];
  float rd = (dh > 0.f) ? (1.f/dh) : 0.f;
  float acc = 0.f;
  for(int i=0; i<cnt; i++){
    int p;
    float ex;
    if(i < CAP){ p = dl[i]; ex = exs[i*8 + h]; }
    else { p = dstlist[o0+i]; ex = __expf(abuf[(size_t)p*8 + h]); }
    acc += ex * rd * bf2f(vbuf[(size_t)p*128 + tid]);
  }
  int t = ntype[d];
  acc += h_bias[t*128 + tid];
  hpre[(size_t)npos[d]*128 + tid] = f2bf(acc);   // write at ntype-sorted row
}

// ---------------- GEMM core w/ LDS A (kept for k_final): 8 waves, 16c each
template<int NC>
__device__ __forceinline__ void gemm64r8(
  const unsigned short* __restrict__ A, int lda,
  const unsigned short* __restrict__ Wf,
  f32x4* acc, int tid)
{
  int lane = tid & 63, w = tid >> 6, m = lane & 15, quad = lane >> 4;
  const unsigned short* p0 = Wf + (size_t)w*NC*512 + lane*8;
  short8 b0[NC];
  #pragma unroll
  for(int c=0;c<NC;c++) b0[c] = *(const short8*)(p0 + c*512);
  #pragma unroll
  for(int i=0;i<4;i++) acc[i] = (f32x4){0.f,0.f,0.f,0.f};
  #pragma unroll
  for(int c=0;c<NC;c++){
    #pragma unroll
    for(int rt=0; rt<4; rt++){
      short8 af = *(const short8*)(A + (rt*16 + m)*lda + c*32 + quad*8);
      acc[rt] = __builtin_amdgcn_mfma_f32_16x16x32_bf16(af, b0[c], acc[rt], 0,0,0);
    }
  }
}

// ---------------- final typed GEMM (Wa) + gate + residual (8 waves)
__global__ __launch_bounds__(512) void k_final(
  const unsigned short* __restrict__ hpre, const unsigned short* __restrict__ Wa_t,
  const int* __restrict__ cnt_n, const int* __restrict__ off_n, const int* __restrict__ nperm,
  const float* __restrict__ skip, const float* __restrict__ src_h, float* __restrict__ out)
{
  __shared__ unsigned short Ah[64*136];
  int bid = blockIdx.x;
  int r = -1, tl0 = 0, accT = 0;
  #pragma unroll
  for(int i=0;i<4;i++){
    int n = cnt_n[i], tt = (n + 63) >> 6;
    if(r < 0 && bid < accT + tt){ r = i; tl0 = bid - accT; }
    accT += tt;
  }
  if(r < 0) return;
  int row0 = off_n[r] + tl0*64;
  int nv = min(64, cnt_n[r] - tl0*64);
  float gate = 1.f / (1.f + __expf(-skip[r]));
  int tid = threadIdx.x;
  int4 z = make_int4(0,0,0,0);
  #pragma unroll
  for(int it=0; it<2; it++){
    int idx = it*512 + tid, row = idx >> 4, c = idx & 15;
    int4 v = z;
    if(row < nv) v = *(const int4*)(hpre + (size_t)(row0+row)*128 + c*8);
    *(int4*)(Ah + row*136 + c*8) = v;
  }
  __syncthreads();
  f32x4 acc[4];
  gemm64r8<4>(Ah, 136, Wa_t + r*16384, acc, tid);
  int lane = tid & 63, w = tid >> 6, m = lane & 15, quad = lane >> 4;
  #pragma unroll
  for(int rt=0; rt<4; rt++)
  #pragma unroll
  for(int reg=0; reg<4; reg++){
    int row = rt*16 + quad*4 + reg;
    if(row < nv){
      int dd = nperm[row0+row];
      int col = w*16 + m;
      out[(size_t)dd*128 + col] = acc[rt][reg]*gate + src_h[(size_t)dd*128 + col]*(1.f - gate);
    }
  }
}

// ---------------------------------------------------------------------------
extern "C" void kernel_launch(void* const* d_in, const int* in_sizes, int n_in,
                              void* d_out, int out_size, void* d_ws, size_t ws_size,
                              hipStream_t stream)
{
  const float* src_h  = (const float*)d_in[0];
  const float* src_tw = (const float*)d_in[1];
  const float* src_tb = (const float*)d_in[2];
  const float* edge_h = (const float*)d_in[3];
  const float* date   = (const float*)d_in[4];
  const int*   src_idx= (const int*)d_in[5];
  const int*   dst_idx= (const int*)d_in[6];
  const int*   etype  = (const int*)d_in[7];
  const int*   ntype  = (const int*)d_in[8];
  const float* Wq     = (const float*)d_in[9];
  const float* Wk     = (const float*)d_in[10];
  const float* Wv     = (const float*)d_in[11];
  const float* Wa     = (const float*)d_in[12];
  const float* h_bias = (const float*)d_in[13];
  const float* skip   = (const float*)d_in[14];
  const float* g_s    = (const float*)d_in[15];
  const float* b_s    = (const float*)d_in[16];
  const float* g_d    = (const float*)d_in[17];
  const float* b_d    = (const float*)d_in[18];
  float* out = (float*)d_out;

  const int E = in_sizes[4];   // date
  const int M = in_sizes[8];   // ntype
  const int Ep = E + 8*63;     // upper bound on padded edge count

  char* base = (char*)d_ws;
  size_t off = 0;
  auto alloc = [&](size_t bytes)->char*{
    off = (off + 255) & ~(size_t)255;
    char* p = base + off; off += bytes; return p;
  };
  // contiguous zero region: cnt_e[8] cur_e[8] cnt_n[4] cur_n[4] cnt_d[M] cur_d[M]
  int* cnt_e = (int*)alloc((size_t)(24 + 2*M)*4);
  int* cur_e = cnt_e + 8;
  int* cnt_n = cur_e + 8;
  int* cur_n = cnt_n + 4;
  int* cnt_d = cur_n + 4;
  int* cur_d = cnt_d + M;
  const int nzero = 24 + 2*M;
  int* off_e = (int*)alloc(9*4);
  int* off_n = (int*)alloc(5*4);
  int* off_d = (int*)alloc((size_t)(M+1)*4);
  int* eperm   = (int*)alloc((size_t)Ep*4);
  int* dstlist = (int*)alloc((size_t)E*4);
  int* nperm   = (int*)alloc((size_t)M*4);
  int* npos    = (int*)alloc((size_t)M*4);
  unsigned short* Wq_t = (unsigned short*)alloc((size_t)8*128*128*2);
  unsigned short* Wk_t = (unsigned short*)alloc((size_t)8*160*128*2);
  unsigned short* Wv_t = (unsigned short*)alloc((size_t)8*160*128*2);
  unsigned short* Wa_t = (unsigned short*)alloc((size_t)4*128*128*2);
  unsigned short* dia_d = (unsigned short*)alloc((size_t)(Ep+16)*128*2);
  unsigned short* dia_s = (unsigned short*)alloc((size_t)(Ep+16)*160*2);
  unsigned short* vbuf  = (unsigned short*)alloc((size_t)Ep*128*2);
  unsigned short* hpre  = (unsigned short*)alloc((size_t)M*128*2);
  float* abuf = (float*)alloc((size_t)Ep*8*4);

  k_zero<<<dim3((nzero+255)/256), dim3(256), 0, stream>>>(cnt_e, nzero);
  k_zero<<<dim3((Ep+255)/256), dim3(256), 0, stream>>>(eperm, Ep);
  k_hist<<<dim3((E+255)/256), dim3(256), 0, stream>>>(etype, dst_idx, ntype, cnt_e, cnt_d, cnt_n, E, M);
  k_scan<<<dim3(1), dim3(1024), 0, stream>>>(cnt_e, off_e, cnt_n, off_n, cnt_d, off_d, M);
  k_scatter<<<dim3((E+255)/256), dim3(256), 0, stream>>>(etype, dst_idx, ntype,
      off_e, cur_e, off_d, cur_d, off_n, cur_n, eperm, dstlist, nperm, npos, E, M);
  k_convw<<<dim3(2048), dim3(256), 0, stream>>>(Wq, Wk, Wv, Wa, Wq_t, Wk_t, Wv_t, Wa_t);
  k_prep<<<dim3((Ep+15)/16), dim3(256), 0, stream>>>(src_h, src_tw, src_tb, edge_h, date,
      src_idx, dst_idx, eperm, g_s, b_s, g_d, b_d, dia_s, dia_d, Ep);
  k_qkv<<<dim3(E/64 + 9), dim3(512), 0, stream>>>(dia_d, dia_s, Wq_t, Wk_t, Wv_t,
      cnt_e, off_e, abuf, vbuf);
  k_aggr<<<dim3(M), dim3(128), 0, stream>>>(abuf, vbuf, dstlist, off_d, npos, ntype, h_bias, hpre);
  k_final<<<dim3(M/64 + 5), dim3(512), 0, stream>>>(hpre, Wa_t, cnt_n, off_n, nperm, skip, src_h, out);
}